// Round 1
// baseline (789.866 us; speedup 1.0000x reference)
//
#include <hip/hip_runtime.h>

typedef short s16x8 __attribute__((ext_vector_type(8)));   // 8 bf16 raw bits
typedef float f32x4 __attribute__((ext_vector_type(4)));
typedef unsigned short u16;

__device__ __forceinline__ u16 f2bf(float x){
    unsigned u = __float_as_uint(x);
    unsigned r = u + 0x7fffu + ((u >> 16) & 1u);
    return (u16)(r >> 16);
}
__device__ __forceinline__ float bfhi2f(unsigned v){ return __uint_as_float(v & 0xFFFF0000u); }
__device__ __forceinline__ float bflo2f(unsigned v){ return __uint_as_float(v << 16); }

// ---------------- weight prep: in[oc][ic][27] fp32 -> out[oc][tap][C] bf16 -----------------
__global__ void prep_w_kernel(const float* __restrict__ in, u16* __restrict__ out, int icShift){
    extern __shared__ u16 lds[];
    const int C = 1 << icShift;
    const int n = C * 27;
    const int oc = blockIdx.x;
    const float* src = in + (size_t)oc * n;
    for (int i = threadIdx.x; i < n; i += blockDim.x) lds[i] = f2bf(src[i]);
    __syncthreads();
    u16* dst = out + (size_t)oc * n;
    for (int j = threadIdx.x; j < n; j += blockDim.x){
        int tap = j >> icShift;
        int ic  = j & (C - 1);
        dst[j] = lds[ic * 27 + tap];
    }
}

// ---------------- ROI align (fp32 in, bf16 out): rbuf[(f*6+b)*9+sp][1024]; row 1728 = 0 ----
__global__ __launch_bounds__(256) void roi_kernel(const float* __restrict__ fmaps,
                                                  const float* __restrict__ boxes,
                                                  u16* __restrict__ rbuf){
    int blk = blockIdx.x;              // 0..1728 ; 1728 is the zero row
    u16* dst = rbuf + (size_t)blk * 1024;
    if (blk == 1728){
        for (int c = threadIdx.x; c < 1024; c += blockDim.x) dst[c] = 0;
        return;
    }
    int f = blk / 54; int r = blk % 54; int b = r / 9; int sp = r % 9;
    int oh = sp / 3, ow = sp % 3;
    const float* bx = boxes + (f * 6 + b) * 4;
    float x1 = bx[0], y1 = bx[1], x2 = bx[2], y2 = bx[3];
    float bw = fmaxf(x2 - x1, 1.0f) * (1.0f / 3.0f);
    float bh = fmaxf(y2 - y1, 1.0f) * (1.0f / 3.0f);
    int iy0[2], iy1[2], ix0[2], ix1[2];
    float ly[2], lx[2];
#pragma unroll
    for (int s = 0; s < 2; ++s){
        float gy = (float)oh + (s + 0.5f) * 0.5f;
        float ys = y1 + bh * gy;
        float y0f = floorf(ys); y0f = fminf(fmaxf(y0f, 0.f), 13.f);
        ly[s] = fminf(fmaxf(ys - y0f, 0.f), 1.f);
        iy0[s] = (int)y0f; iy1[s] = min(iy0[s] + 1, 13);
        float gx = (float)ow + (s + 0.5f) * 0.5f;
        float xs = x1 + bw * gx;
        float x0f = floorf(xs); x0f = fminf(fmaxf(x0f, 0.f), 13.f);
        lx[s] = fminf(fmaxf(xs - x0f, 0.f), 1.f);
        ix0[s] = (int)x0f; ix1[s] = min(ix0[s] + 1, 13);
    }
    int offs[16]; float wts[16]; int idx = 0;
#pragma unroll
    for (int sy = 0; sy < 2; ++sy)
#pragma unroll
        for (int sx = 0; sx < 2; ++sx){
            float wy1v = ly[sy], wy0v = 1.f - wy1v;
            float wx1v = lx[sx], wx0v = 1.f - wx1v;
            offs[idx] = iy0[sy] * 14 + ix0[sx]; wts[idx] = wy0v * wx0v; idx++;
            offs[idx] = iy0[sy] * 14 + ix1[sx]; wts[idx] = wy0v * wx1v; idx++;
            offs[idx] = iy1[sy] * 14 + ix0[sx]; wts[idx] = wy1v * wx0v; idx++;
            offs[idx] = iy1[sy] * 14 + ix1[sx]; wts[idx] = wy1v * wx1v; idx++;
        }
    const float* fb0 = fmaps + (size_t)f * 1024 * 196;
    for (int c = threadIdx.x; c < 1024; c += blockDim.x){
        const float* fm = fb0 + (size_t)c * 196;
        float acc = 0.f;
#pragma unroll
        for (int i = 0; i < 16; ++i) acc += fm[offs[i]] * wts[i];
        dst[c] = f2bf(acc * 0.25f);
    }
}

// ---------------- rowidx[fb][t] = rbuf row base (r*9) of matched person, or -1 ------------
__global__ void rowidx_kernel(const int* __restrict__ pid, int* __restrict__ rowidx){
    int i = blockIdx.x * blockDim.x + threadIdx.x;   // 960 = 192*5
    if (i >= 960) return;
    int fb = i / 5, t = i % 5;
    int f = fb / 6, b = fb % 6;
    int start = max(f - 2, 0);
    int end = min(start + 4, 31);
    int span = end - start;
    int g = start + (t * span) / 4;
    int p = pid[f * 6 + b];
    int r = -1;
#pragma unroll
    for (int j = 0; j < 6; ++j)
        if (pid[g * 6 + j] == p){ r = (g * 6 + j) * 9; break; }
    rowidx[i] = r;
}

// ---------------- stage A: per-tap GEMM  P[tap][r][oc] = rbuf[r] . Wt1[oc][tap] -----------
#define KP1 72    // LDS row stride (u16) during K-loop
#define EP1 136   // LDS row stride (u16) during epilogue staging (272 B, 16B-multiple)

__global__ __launch_bounds__(256) void tapgemm_kernel(
        const u16* __restrict__ Wt1,     // [512][27][1024] bf16
        const u16* __restrict__ rb,      // [1729][1024] bf16 (row 1728 = 0)
        u16* __restrict__ P)             // [27][1728][512] bf16
{
    __shared__ u16 smem[2 * 128 * KP1];  // 36,864 B; reused as [128][EP1] (34,816 B) in epilogue
    u16* As = smem;
    u16* Bs = smem + 128 * KP1;
    const int tid = threadIdx.x;
    const int m0 = blockIdx.x * 128;     // oc
    const int n0 = blockIdx.y * 128;     // r
    const int tap = blockIdx.z;

    const int arow = tid >> 1, half = tid & 1;          // 128 rows, 64 B per thread
    const u16* aptr = Wt1 + (size_t)(m0 + arow) * 27648 + tap * 1024 + half * 32;
    const int brow = min(n0 + arow, 1728);              // clamp to zero row
    const u16* bptr = rb + (size_t)brow * 1024 + half * 32;

    const int lane = tid & 63, wv = tid >> 6;
    const int wm = (wv & 1) * 64, wn = (wv >> 1) * 64;
    const int lid = lane & 15, q = lane >> 4;
    f32x4 acc[4][4];
#pragma unroll
    for (int i = 0; i < 4; ++i)
#pragma unroll
        for (int j = 0; j < 4; ++j) acc[i][j] = (f32x4){0.f, 0.f, 0.f, 0.f};

    uint4 aC[4], bC[4], aN[4], bN[4];
#pragma unroll
    for (int j = 0; j < 4; ++j){
        aC[j] = *(const uint4*)(aptr + j * 8);
        bC[j] = *(const uint4*)(bptr + j * 8);
    }
    for (int kt = 0; kt < 16; ++kt){
        __syncthreads();
        {
            u16* as = &As[arow * KP1 + half * 32];
            u16* bs = &Bs[arow * KP1 + half * 32];
#pragma unroll
            for (int j = 0; j < 4; ++j){
                *(uint4*)(as + j * 8) = aC[j];
                *(uint4*)(bs + j * 8) = bC[j];
            }
        }
        __syncthreads();
        if (kt + 1 < 16){
            const u16* ap = aptr + (kt + 1) * 64;
            const u16* bp = bptr + (kt + 1) * 64;
#pragma unroll
            for (int j = 0; j < 4; ++j){
                aN[j] = *(const uint4*)(ap + j * 8);
                bN[j] = *(const uint4*)(bp + j * 8);
            }
        }
#pragma unroll
        for (int ks = 0; ks < 2; ++ks){
            s16x8 af[4], bf[4];
#pragma unroll
            for (int mi = 0; mi < 4; ++mi) af[mi] = *(const s16x8*)&As[(wm + mi * 16 + lid) * KP1 + ks * 32 + q * 8];
#pragma unroll
            for (int ni = 0; ni < 4; ++ni) bf[ni] = *(const s16x8*)&Bs[(wn + ni * 16 + lid) * KP1 + ks * 32 + q * 8];
#pragma unroll
            for (int mi = 0; mi < 4; ++mi)
#pragma unroll
                for (int ni = 0; ni < 4; ++ni)
                    acc[mi][ni] = __builtin_amdgcn_mfma_f32_16x16x32_bf16(af[mi], bf[ni], acc[mi][ni], 0, 0, 0);
        }
#pragma unroll
        for (int j = 0; j < 4; ++j){ aC[j] = aN[j]; bC[j] = bN[j]; }
    }

    // ---- epilogue: stage bf16 tile in LDS, then fully coalesced linear writeout ----
    // Old path stored 8 B/lane to 16 rows @1024 B stride -> 8.9x HBM write amplification.
    __syncthreads();                     // all waves done reading As/Bs
#pragma unroll
    for (int mi = 0; mi < 4; ++mi){
        const int col = wm + mi * 16 + q * 4;          // m-local (oc)
#pragma unroll
        for (int ni = 0; ni < 4; ++ni){
            const int row = wn + ni * 16 + lid;        // n-local (r)
            ushort4 o;
            o.x = f2bf(acc[mi][ni][0]);
            o.y = f2bf(acc[mi][ni][1]);
            o.z = f2bf(acc[mi][ni][2]);
            o.w = f2bf(acc[mi][ni][3]);
            *(ushort4*)(smem + row * EP1 + col) = o;
        }
    }
    __syncthreads();
    // 128 rows x 256 B per row-segment; each 16-lane group writes one full row segment
    // (four complete 64 B lines) -> every HBM line produced by a single store instr.
    u16* Pt = P + (size_t)tap * 1728 * 512;
    const int trow = tid >> 4;          // 0..15
    const int tcol = tid & 15;          // 16 B chunk within the 256 B segment
#pragma unroll
    for (int it = 0; it < 8; ++it){
        const int rl = it * 16 + trow;
        const int n = n0 + rl;
        if (n < 1728){
            uint4 v = *(const uint4*)(smem + rl * EP1 + tcol * 8);
            *(uint4*)(Pt + (size_t)n * 512 + m0 + tcol * 8) = v;
        }
    }
}

// ---------------- stage B: y[n][oc] = relu(b1 + sum_tap P[tap][src(n,tap)][oc]) -----------
__global__ __launch_bounds__(256) void reduce_kernel(
        const unsigned* __restrict__ P32,   // [27][1728][256] (u32 = 2 bf16)
        const int* __restrict__ rowidx,     // [192][5]
        const float* __restrict__ b1,       // [512]
        unsigned* __restrict__ y32)         // [8640][256]
{
    __shared__ int rows[27];
    const int n = blockIdx.x;             // 0..8639
    const int tid = threadIdx.x;
    const int fb = n / 45, rr = n % 45;
    const int od = rr / 9, oh = (rr % 9) / 3, ow = rr % 3;
    if (tid < 27){
        int kd = tid / 9, kh = (tid % 9) / 3, kw = tid % 3;
        int t = od + kd - 1, h = oh + kh - 1, w = ow + kw - 1;
        int row = -1;
        if ((unsigned)t < 5u && (unsigned)h < 3u && (unsigned)w < 3u){
            int rbv = rowidx[fb * 5 + t];
            if (rbv >= 0) row = rbv + h * 3 + w;
        }
        rows[tid] = row;
    }
    __syncthreads();
    float a0 = 0.f, a1 = 0.f;
#pragma unroll
    for (int tap = 0; tap < 27; ++tap){
        int r = rows[tap];
        if (r >= 0){
            unsigned v = P32[((size_t)(tap * 1728 + r) << 8) + tid];
            a0 += bflo2f(v);
            a1 += bfhi2f(v);
        }
    }
    a0 = fmaxf(a0 + b1[tid * 2], 0.f);
    a1 = fmaxf(a1 + b1[tid * 2 + 1], 0.f);
    y32[(size_t)n * 256 + tid] = (unsigned)f2bf(a0) | ((unsigned)f2bf(a1) << 16);
}

// ---------------- GEMM2: conv1b, 64x64 tile, BK=64, split-K=8 -----------------------------
#define EP2 68   // fp32 LDS row stride in epilogue (272 B, 16B-multiple)

__global__ __launch_bounds__(256) void gemm2_kernel(
        const u16* __restrict__ Wt2,   // [256][13824] bf16, k = tap*512+ic
        const u16* __restrict__ y,     // [8640][512] bf16; row n=fb*45+od*9+sp
        float* __restrict__ zpart)     // [8][576][256]
{
    __shared__ u16 smem[2 * 64 * KP1];   // 18,432 B; reused as float[64][EP2] (17,408 B)
    u16* As = smem;
    u16* Bs = smem + 64 * KP1;
    const int tid = threadIdx.x;
    const int m0 = blockIdx.x * 64;
    const int n0 = blockIdx.y * 64;
    const int kz = blockIdx.z;
    const int kbase = kz * 1728;            // 27 chunks of 64
    const int arow = tid >> 2, seg = tid & 3;
    const u16* aptr = Wt2 + (size_t)(m0 + arow) * 13824 + kbase + seg * 16;
    const int n2 = n0 + arow;
    const int fb = n2 / 3, od2 = n2 - fb * 3;
    const u16* bptr = y + (size_t)(fb * 45 + od2 * 9) * 512 + kbase + seg * 16;

    const int lane = tid & 63, wv = tid >> 6;
    const int wm = (wv & 1) * 32, wn = (wv >> 1) * 32;
    const int lid = lane & 15, q = lane >> 4;
    f32x4 acc[2][2];
#pragma unroll
    for (int i = 0; i < 2; ++i)
#pragma unroll
        for (int j = 0; j < 2; ++j) acc[i][j] = (f32x4){0.f, 0.f, 0.f, 0.f};

    uint4 aC[2], bC[2], aN[2], bN[2];
#pragma unroll
    for (int j = 0; j < 2; ++j){
        aC[j] = *(const uint4*)(aptr + j * 8);
        bC[j] = *(const uint4*)(bptr + j * 8);
    }
    for (int kt = 0; kt < 27; ++kt){
        __syncthreads();
        {
            u16* as = &As[arow * KP1 + seg * 16];
            u16* bs = &Bs[arow * KP1 + seg * 16];
#pragma unroll
            for (int j = 0; j < 2; ++j){
                *(uint4*)(as + j * 8) = aC[j];
                *(uint4*)(bs + j * 8) = bC[j];
            }
        }
        __syncthreads();
        if (kt + 1 < 27){
            const u16* ap = aptr + (kt + 1) * 64;
            const u16* bp = bptr + (kt + 1) * 64;
#pragma unroll
            for (int j = 0; j < 2; ++j){
                aN[j] = *(const uint4*)(ap + j * 8);
                bN[j] = *(const uint4*)(bp + j * 8);
            }
        }
#pragma unroll
        for (int ks = 0; ks < 2; ++ks){
            s16x8 af[2], bf[2];
#pragma unroll
            for (int mi = 0; mi < 2; ++mi) af[mi] = *(const s16x8*)&As[(wm + mi * 16 + lid) * KP1 + ks * 32 + q * 8];
#pragma unroll
            for (int ni = 0; ni < 2; ++ni) bf[ni] = *(const s16x8*)&Bs[(wn + ni * 16 + lid) * KP1 + ks * 32 + q * 8];
#pragma unroll
            for (int mi = 0; mi < 2; ++mi)
#pragma unroll
                for (int ni = 0; ni < 2; ++ni)
                    acc[mi][ni] = __builtin_amdgcn_mfma_f32_16x16x32_bf16(af[mi], bf[ni], acc[mi][ni], 0, 0, 0);
        }
#pragma unroll
        for (int j = 0; j < 2; ++j){ aC[j] = aN[j]; bC[j] = bN[j]; }
    }

    // ---- epilogue: stage fp32 tile in LDS, then coalesced linear writeout ----
    __syncthreads();
    float* epf = (float*)smem;           // [64][EP2]
#pragma unroll
    for (int mi = 0; mi < 2; ++mi){
        const int col = wm + mi * 16 + q * 4;
#pragma unroll
        for (int ni = 0; ni < 2; ++ni){
            const int row = wn + ni * 16 + lid;
            float4 o = make_float4(acc[mi][ni][0], acc[mi][ni][1], acc[mi][ni][2], acc[mi][ni][3]);
            *(float4*)(epf + row * EP2 + col) = o;
        }
    }
    __syncthreads();
    // 64 rows x 256 B per row-segment in zpart; 16-lane groups write full segments.
    const int trow = tid >> 4;          // 0..15
    const int tcol = tid & 15;          // 16 B chunk
#pragma unroll
    for (int it = 0; it < 4; ++it){
        const int rl = it * 16 + trow;
        float4 v = *(const float4*)(epf + rl * EP2 + tcol * 4);
        *(float4*)(zpart + ((size_t)kz * 576 + n0 + rl) * 256 + m0 + tcol * 4) = v;
    }
}

// ---------------- final: sum split-K + bias + relu + max over D + FC 256->27 (fp32 out) ----
__global__ __launch_bounds__(256) void final_kernel(
        const float* __restrict__ zpart, const float* __restrict__ b2,
        const float* __restrict__ fcw, const float* __restrict__ fcb,
        float* __restrict__ out){
    __shared__ float smv[256];
    const int fb = blockIdx.x, tid = threadIdx.x;
    const float bias = b2[tid];
    float mv = 0.f;
#pragma unroll
    for (int od = 0; od < 3; ++od){
        const int n = fb * 3 + od;
        float s = 0.f;
#pragma unroll
        for (int sp = 0; sp < 8; ++sp) s += zpart[((size_t)sp * 576 + n) * 256 + tid];
        s = fmaxf(s + bias, 0.f);
        mv = fmaxf(mv, s);
    }
    smv[tid] = mv;
    __syncthreads();
    const int wv = tid >> 6, lane = tid & 63;
    for (int cls = wv; cls < 27; cls += 4){
        const float* wrow = fcw + cls * 256;
        float s = 0.f;
#pragma unroll
        for (int j = 0; j < 4; ++j) s += smv[lane + j * 64] * wrow[lane + j * 64];
#pragma unroll
        for (int off = 32; off > 0; off >>= 1) s += __shfl_xor(s, off);
        if (lane == 0) out[fb * 27 + cls] = s + fcb[cls];
    }
}

extern "C" void kernel_launch(void* const* d_in, const int* in_sizes, int n_in,
                              void* d_out, int out_size, void* d_ws, size_t ws_size,
                              hipStream_t stream){
    const float* fmaps = (const float*)d_in[0];
    const float* boxes = (const float*)d_in[1];
    const int*   pid   = (const int*)d_in[2];
    const float* w1    = (const float*)d_in[3];
    const float* b1    = (const float*)d_in[4];
    const float* w2    = (const float*)d_in[5];
    const float* b2    = (const float*)d_in[6];
    const float* fcw   = (const float*)d_in[7];
    const float* fcb   = (const float*)d_in[8];
    float* out = (float*)d_out;

    // ---- workspace layout: TOTAL 86,710,528 B (86.7 MB) ----
    // [rbuf 3,541,248][rowidx 4,096][Wt1 28,311,552 | alias: y 8,847,360 + zpart 4,718,592]
    // [Wt2 7,077,888][P 47,775,744]
    char* ws = (char*)d_ws;
    u16*   rbuf  = (u16*)(ws);
    int*   rowidx= (int*)(ws + 3541248);
    u16*   Wt1   = (u16*)(ws + 3545344);
    u16*   y     = (u16*)(ws + 3545344);                    // aliases Wt1 (dead after tapgemm)
    float* zpart = (float*)(ws + 3545344 + 8847360);        // also inside Wt1 region
    u16*   Wt2   = (u16*)(ws + 3545344 + 28311552);
    u16*   P     = (u16*)(ws + 3545344 + 28311552 + 7077888);

    hipLaunchKernelGGL(prep_w_kernel, dim3(512), dim3(256), 1024 * 27 * 2, stream, w1, Wt1, 10);
    hipLaunchKernelGGL(prep_w_kernel, dim3(256), dim3(256), 512 * 27 * 2, stream, w2, Wt2, 9);
    hipLaunchKernelGGL(roi_kernel, dim3(1729), dim3(256), 0, stream, fmaps, boxes, rbuf);
    hipLaunchKernelGGL(rowidx_kernel, dim3(4), dim3(256), 0, stream, pid, rowidx);
    hipLaunchKernelGGL(tapgemm_kernel, dim3(4, 14, 27), dim3(256), 0, stream, Wt1, rbuf, P);
    hipLaunchKernelGGL(reduce_kernel, dim3(8640), dim3(256), 0, stream,
                       (const unsigned*)P, rowidx, b1, (unsigned*)y);
    hipLaunchKernelGGL(gemm2_kernel, dim3(4, 9, 8), dim3(256), 0, stream, Wt2, y, zpart);
    hipLaunchKernelGGL(final_kernel, dim3(192), dim3(256), 0, stream, zpart, b2, fcw, fcb, out);
}

// Round 3
// 446.104 us; speedup vs baseline: 1.7706x; 1.7706x over previous
//
#include <hip/hip_runtime.h>

typedef short s16x8 __attribute__((ext_vector_type(8)));   // 8 bf16 raw bits
typedef float f32x4 __attribute__((ext_vector_type(4)));
typedef unsigned u32x4 __attribute__((ext_vector_type(4)));
typedef unsigned short u16;

__device__ __forceinline__ u16 f2bf(float x){
    unsigned u = __float_as_uint(x);
    unsigned r = u + 0x7fffu + ((u >> 16) & 1u);
    return (u16)(r >> 16);
}
__device__ __forceinline__ float bfhi2f(unsigned v){ return __uint_as_float(v & 0xFFFF0000u); }
__device__ __forceinline__ float bflo2f(unsigned v){ return __uint_as_float(v << 16); }

// async global->LDS, 16B per lane; LDS dest is wave-uniform base + lane*16 (HW), src is per-lane
#define GLOAD_LDS16(g, l) __builtin_amdgcn_global_load_lds( \
        (const __attribute__((address_space(1))) void*)(g), \
        (__attribute__((address_space(3))) void*)(l), 16, 0, 0)

// ---------------- weight prep: in[oc][ic][27] fp32 -> out[oc][tap][C] bf16 -----------------
__global__ void prep_w_kernel(const float* __restrict__ in, u16* __restrict__ out, int icShift){
    extern __shared__ u16 lds[];
    const int C = 1 << icShift;
    const int n = C * 27;
    const int oc = blockIdx.x;
    const float* src = in + (size_t)oc * n;
    for (int i = threadIdx.x; i < n; i += blockDim.x) lds[i] = f2bf(src[i]);
    __syncthreads();
    u16* dst = out + (size_t)oc * n;
    for (int j = threadIdx.x; j < n; j += blockDim.x){
        int tap = j >> icShift;
        int ic  = j & (C - 1);
        dst[j] = lds[ic * 27 + tap];
    }
}

// ---------------- ROI align (fp32 in, bf16 out): rbuf[(f*6+b)*9+sp][1024]; row 1728 = 0 ----
__global__ __launch_bounds__(256) void roi_kernel(const float* __restrict__ fmaps,
                                                  const float* __restrict__ boxes,
                                                  u16* __restrict__ rbuf){
    int blk = blockIdx.x;              // 0..1728 ; 1728 is the zero row
    u16* dst = rbuf + (size_t)blk * 1024;
    if (blk == 1728){
        for (int c = threadIdx.x; c < 1024; c += blockDim.x) dst[c] = 0;
        return;
    }
    int f = blk / 54; int r = blk % 54; int b = r / 9; int sp = r % 9;
    int oh = sp / 3, ow = sp % 3;
    const float* bx = boxes + (f * 6 + b) * 4;
    float x1 = bx[0], y1 = bx[1], x2 = bx[2], y2 = bx[3];
    float bw = fmaxf(x2 - x1, 1.0f) * (1.0f / 3.0f);
    float bh = fmaxf(y2 - y1, 1.0f) * (1.0f / 3.0f);
    int iy0[2], iy1[2], ix0[2], ix1[2];
    float ly[2], lx[2];
#pragma unroll
    for (int s = 0; s < 2; ++s){
        float gy = (float)oh + (s + 0.5f) * 0.5f;
        float ys = y1 + bh * gy;
        float y0f = floorf(ys); y0f = fminf(fmaxf(y0f, 0.f), 13.f);
        ly[s] = fminf(fmaxf(ys - y0f, 0.f), 1.f);
        iy0[s] = (int)y0f; iy1[s] = min(iy0[s] + 1, 13);
        float gx = (float)ow + (s + 0.5f) * 0.5f;
        float xs = x1 + bw * gx;
        float x0f = floorf(xs); x0f = fminf(fmaxf(x0f, 0.f), 13.f);
        lx[s] = fminf(fmaxf(xs - x0f, 0.f), 1.f);
        ix0[s] = (int)x0f; ix1[s] = min(ix0[s] + 1, 13);
    }
    int offs[16]; float wts[16]; int idx = 0;
#pragma unroll
    for (int sy = 0; sy < 2; ++sy)
#pragma unroll
        for (int sx = 0; sx < 2; ++sx){
            float wy1v = ly[sy], wy0v = 1.f - wy1v;
            float wx1v = lx[sx], wx0v = 1.f - wx1v;
            offs[idx] = iy0[sy] * 14 + ix0[sx]; wts[idx] = wy0v * wx0v; idx++;
            offs[idx] = iy0[sy] * 14 + ix1[sx]; wts[idx] = wy0v * wx1v; idx++;
            offs[idx] = iy1[sy] * 14 + ix0[sx]; wts[idx] = wy1v * wx0v; idx++;
            offs[idx] = iy1[sy] * 14 + ix1[sx]; wts[idx] = wy1v * wx1v; idx++;
        }
    const float* fb0 = fmaps + (size_t)f * 1024 * 196;
    for (int c = threadIdx.x; c < 1024; c += blockDim.x){
        const float* fm = fb0 + (size_t)c * 196;
        float acc = 0.f;
#pragma unroll
        for (int i = 0; i < 16; ++i) acc += fm[offs[i]] * wts[i];
        dst[c] = f2bf(acc * 0.25f);
    }
}

// ---------------- rowidx[fb][t] = rbuf row base (r*9) of matched person, or -1 ------------
__global__ void rowidx_kernel(const int* __restrict__ pid, int* __restrict__ rowidx){
    int i = blockIdx.x * blockDim.x + threadIdx.x;   // 960 = 192*5
    if (i >= 960) return;
    int fb = i / 5, t = i % 5;
    int f = fb / 6, b = fb % 6;
    int start = max(f - 2, 0);
    int end = min(start + 4, 31);
    int span = end - start;
    int g = start + (t * span) / 4;
    int p = pid[f * 6 + b];
    int r = -1;
#pragma unroll
    for (int j = 0; j < 6; ++j)
        if (pid[g * 6 + j] == p){ r = (g * 6 + j) * 9; break; }
    rowidx[i] = r;
}

// ---------------- stage A: per-tap GEMM  P[tap][mb][r][128] = rbuf[r] . Wt1[oc][tap] ------
// m97 structure: 128x128 tile, BK=64, global_load_lds w16, linear LDS [128][64] u16 with
// XOR bank-swizzle applied as pre-swizzled GLOBAL source + swizzled ds_read (rule #21).
__global__ __launch_bounds__(256, 4) void tapgemm_kernel(
        const u16* __restrict__ Wt1,     // [512][27][1024] bf16
        const u16* __restrict__ rb,      // [1729][1024] bf16 (row 1728 = 0)
        u16* __restrict__ P)             // [27][4][1728][128] bf16 (block-contiguous tiles)
{
    __shared__ u16 lds[16384];           // 32 KB: As [128][64] + Bs [128][64]
    u16* As = lds;
    u16* Bs = lds + 8192;
    const int tid = threadIdx.x;
    const int m0 = blockIdx.x * 128;     // oc
    const int n0 = blockIdx.y * 128;     // r
    const int tap = blockIdx.z;

    // ---- staging geometry: issue (w,j) covers rows w*32+j*8 .. +8 of the 128x64 tile ----
    const int w   = tid >> 6;            // wave
    const int l   = tid & 63;
    const int sub = l >> 3;              // row within 8-row group
    const int csw = (l & 7) ^ sub;       // logical K-chunk for this lane (pre-swizzled source)
    const int rowb = w * 32 + sub;
    const char* gA = (const char*)Wt1 + (size_t)(m0 + rowb) * 55296 + tap * 2048 + csw * 16;
    const char* gB[4];
#pragma unroll
    for (int j = 0; j < 4; ++j){
        int gr = min(n0 + rowb + j * 8, 1728);       // clamp to zero row
        gB[j] = (const char*)rb + (size_t)gr * 2048 + csw * 16;
    }

    const int lane = tid & 63, wv = tid >> 6;
    const int wm = (wv & 1) * 64, wn = (wv >> 1) * 64;
    const int lid = lane & 15, q = lane >> 4;
    const int xr = (lid & 7) << 4;       // read-side swizzle (row&7 == lid&7 for all frags)
    f32x4 acc[4][4];
#pragma unroll
    for (int i = 0; i < 4; ++i)
#pragma unroll
        for (int j = 0; j < 4; ++j) acc[i][j] = (f32x4){0.f, 0.f, 0.f, 0.f};

    for (int kt = 0; kt < 16; ++kt){
        __syncthreads();                 // prior tile fully consumed
#pragma unroll
        for (int j = 0; j < 4; ++j)
            GLOAD_LDS16(gA + (size_t)j * 442368 + kt * 128, &As[(w * 4 + j) * 512]);
#pragma unroll
        for (int j = 0; j < 4; ++j)
            GLOAD_LDS16(gB[j] + kt * 128, &Bs[(w * 4 + j) * 512]);
        __syncthreads();                 // vmcnt drain: staged data visible
#pragma unroll
        for (int ks = 0; ks < 2; ++ks){
            s16x8 af[4], bf[4];
            const int cb = ks * 64 + q * 16;
#pragma unroll
            for (int mi = 0; mi < 4; ++mi)
                af[mi] = *(const s16x8*)((const char*)As + (wm + mi * 16 + lid) * 128 + (cb ^ xr));
#pragma unroll
            for (int ni = 0; ni < 4; ++ni)
                bf[ni] = *(const s16x8*)((const char*)Bs + (wn + ni * 16 + lid) * 128 + (cb ^ xr));
#pragma unroll
            for (int mi = 0; mi < 4; ++mi)
#pragma unroll
                for (int ni = 0; ni < 4; ++ni)
                    acc[mi][ni] = __builtin_amdgcn_mfma_f32_16x16x32_bf16(af[mi], bf[ni], acc[mi][ni], 0, 0, 0);
        }
    }

    // ---- epilogue: LDS-transpose (swizzled, [128 r][256 B]) + contiguous NT writeout ----
    __syncthreads();
#pragma unroll
    for (int mi = 0; mi < 4; ++mi){
        const int colb = (wm + mi * 16 + q * 4) * 2;   // oc-local byte col
#pragma unroll
        for (int ni = 0; ni < 4; ++ni){
            const int row = wn + ni * 16 + lid;        // r-local
            ushort4 o;
            o.x = f2bf(acc[mi][ni][0]);
            o.y = f2bf(acc[mi][ni][1]);
            o.z = f2bf(acc[mi][ni][2]);
            o.w = f2bf(acc[mi][ni][3]);
            *(ushort4*)((char*)lds + row * 256 + (colb ^ xr)) = o;
        }
    }
    __syncthreads();
    // block tile = ONE contiguous 32 KB span of P; stream it out with NT full-line stores
    u16* Pt = P + (((size_t)tap * 4 + blockIdx.x) * 1728 + n0) * 128;
    const int trow = tid >> 4;          // 0..15
    const int c    = tid & 15;          // 16 B chunk within the 256 B row
#pragma unroll
    for (int it = 0; it < 8; ++it){
        const int rl = it * 16 + trow;
        if (n0 + rl < 1728){
            const int pc = (c & 8) | ((c & 7) ^ (rl & 7));
            u32x4 v = *(const u32x4*)((const char*)lds + rl * 256 + pc * 16);
            __builtin_nontemporal_store(v, (u32x4*)(Pt + (size_t)rl * 128 + c * 8));
        }
    }
}

// ---------------- stage B: y[n][oc] = relu(b1 + sum_tap P[tap][mb][src][128]) -------------
__global__ __launch_bounds__(256) void reduce_kernel(
        const unsigned* __restrict__ P32,   // [27][4][1728][64] (u32 = 2 bf16)
        const int* __restrict__ rowidx,     // [192][5]
        const float* __restrict__ b1,       // [512]
        unsigned* __restrict__ y32)         // [8640][256]
{
    __shared__ int rows[27];
    const int n = blockIdx.x;             // 0..8639
    const int tid = threadIdx.x;
    const int fb = n / 45, rr = n % 45;
    const int od = rr / 9, oh = (rr % 9) / 3, ow = rr % 3;
    if (tid < 27){
        int kd = tid / 9, kh = (tid % 9) / 3, kw = tid % 3;
        int t = od + kd - 1, h = oh + kh - 1, w = ow + kw - 1;
        int row = -1;
        if ((unsigned)t < 5u && (unsigned)h < 3u && (unsigned)w < 3u){
            int rbv = rowidx[fb * 5 + t];
            if (rbv >= 0) row = rbv + h * 3 + w;
        }
        rows[tid] = row;
    }
    __syncthreads();
    const int mb = tid >> 6;              // oc-block of this thread's u32 pair
    const int lc = tid & 63;
    float a0 = 0.f, a1 = 0.f;
#pragma unroll
    for (int tap = 0; tap < 27; ++tap){
        int r = rows[tap];
        if (r >= 0){
            unsigned v = P32[(((size_t)tap * 4 + mb) * 1728 + r) * 64 + lc];
            a0 += bflo2f(v);
            a1 += bfhi2f(v);
        }
    }
    a0 = fmaxf(a0 + b1[tid * 2], 0.f);
    a1 = fmaxf(a1 + b1[tid * 2 + 1], 0.f);
    y32[(size_t)n * 256 + tid] = (unsigned)f2bf(a0) | ((unsigned)f2bf(a1) << 16);
}

// ---------------- GEMM2: conv1b, 64x64 tile, BK=64, split-K=8 -----------------------------
#define KP1 72   // LDS row stride (u16)

__global__ __launch_bounds__(256) void gemm2_kernel(
        const u16* __restrict__ Wt2,   // [256][13824] bf16, k = tap*512+ic
        const u16* __restrict__ y,     // [8640][512] bf16; row n=fb*45+od*9+sp
        float* __restrict__ zpart)     // [8][576][256]
{
    __shared__ u16 As[64 * KP1];
    __shared__ u16 Bs[64 * KP1];
    const int tid = threadIdx.x;
    const int m0 = blockIdx.x * 64;
    const int n0 = blockIdx.y * 64;
    const int kz = blockIdx.z;
    const int kbase = kz * 1728;            // 27 chunks of 64
    const int arow = tid >> 2, seg = tid & 3;
    const u16* aptr = Wt2 + (size_t)(m0 + arow) * 13824 + kbase + seg * 16;
    const int n2 = n0 + arow;
    const int fb = n2 / 3, od2 = n2 - fb * 3;
    const u16* bptr = y + (size_t)(fb * 45 + od2 * 9) * 512 + kbase + seg * 16;

    const int lane = tid & 63, wv = tid >> 6;
    const int wm = (wv & 1) * 32, wn = (wv >> 1) * 32;
    const int lid = lane & 15, q = lane >> 4;
    f32x4 acc[2][2];
#pragma unroll
    for (int i = 0; i < 2; ++i)
#pragma unroll
        for (int j = 0; j < 2; ++j) acc[i][j] = (f32x4){0.f, 0.f, 0.f, 0.f};

    uint4 aC[2], bC[2], aN[2], bN[2];
#pragma unroll
    for (int j = 0; j < 2; ++j){
        aC[j] = *(const uint4*)(aptr + j * 8);
        bC[j] = *(const uint4*)(bptr + j * 8);
    }
    for (int kt = 0; kt < 27; ++kt){
        __syncthreads();
        {
            u16* as = &As[arow * KP1 + seg * 16];
            u16* bs = &Bs[arow * KP1 + seg * 16];
#pragma unroll
            for (int j = 0; j < 2; ++j){
                *(uint4*)(as + j * 8) = aC[j];
                *(uint4*)(bs + j * 8) = bC[j];
            }
        }
        __syncthreads();
        if (kt + 1 < 27){
            const u16* ap = aptr + (kt + 1) * 64;
            const u16* bp = bptr + (kt + 1) * 64;
#pragma unroll
            for (int j = 0; j < 2; ++j){
                aN[j] = *(const uint4*)(ap + j * 8);
                bN[j] = *(const uint4*)(bp + j * 8);
            }
        }
#pragma unroll
        for (int ks = 0; ks < 2; ++ks){
            s16x8 af[2], bf[2];
#pragma unroll
            for (int mi = 0; mi < 2; ++mi) af[mi] = *(const s16x8*)&As[(wm + mi * 16 + lid) * KP1 + ks * 32 + q * 8];
#pragma unroll
            for (int ni = 0; ni < 2; ++ni) bf[ni] = *(const s16x8*)&Bs[(wn + ni * 16 + lid) * KP1 + ks * 32 + q * 8];
#pragma unroll
            for (int mi = 0; mi < 2; ++mi)
#pragma unroll
                for (int ni = 0; ni < 2; ++ni)
                    acc[mi][ni] = __builtin_amdgcn_mfma_f32_16x16x32_bf16(af[mi], bf[ni], acc[mi][ni], 0, 0, 0);
        }
#pragma unroll
        for (int j = 0; j < 2; ++j){ aC[j] = aN[j]; bC[j] = bN[j]; }
    }
#pragma unroll
    for (int mi = 0; mi < 2; ++mi){
        const int mbase = m0 + wm + mi * 16 + q * 4;
#pragma unroll
        for (int ni = 0; ni < 2; ++ni){
            const int n = n0 + wn + ni * 16 + lid;
            float4 o = make_float4(acc[mi][ni][0], acc[mi][ni][1], acc[mi][ni][2], acc[mi][ni][3]);
            *(float4*)(zpart + ((size_t)kz * 576 + n) * 256 + mbase) = o;
        }
    }
}

// ---------------- final: sum split-K + bias + relu + max over D + FC 256->27 (fp32 out) ----
__global__ __launch_bounds__(256) void final_kernel(
        const float* __restrict__ zpart, const float* __restrict__ b2,
        const float* __restrict__ fcw, const float* __restrict__ fcb,
        float* __restrict__ out){
    __shared__ float smv[256];
    const int fb = blockIdx.x, tid = threadIdx.x;
    const float bias = b2[tid];
    float mv = 0.f;
#pragma unroll
    for (int od = 0; od < 3; ++od){
        const int n = fb * 3 + od;
        float s = 0.f;
#pragma unroll
        for (int sp = 0; sp < 8; ++sp) s += zpart[((size_t)sp * 576 + n) * 256 + tid];
        s = fmaxf(s + bias, 0.f);
        mv = fmaxf(mv, s);
    }
    smv[tid] = mv;
    __syncthreads();
    const int wv = tid >> 6, lane = tid & 63;
    for (int cls = wv; cls < 27; cls += 4){
        const float* wrow = fcw + cls * 256;
        float s = 0.f;
#pragma unroll
        for (int j = 0; j < 4; ++j) s += smv[lane + j * 64] * wrow[lane + j * 64];
#pragma unroll
        for (int off = 32; off > 0; off >>= 1) s += __shfl_xor(s, off);
        if (lane == 0) out[fb * 27 + cls] = s + fcb[cls];
    }
}

extern "C" void kernel_launch(void* const* d_in, const int* in_sizes, int n_in,
                              void* d_out, int out_size, void* d_ws, size_t ws_size,
                              hipStream_t stream){
    const float* fmaps = (const float*)d_in[0];
    const float* boxes = (const float*)d_in[1];
    const int*   pid   = (const int*)d_in[2];
    const float* w1    = (const float*)d_in[3];
    const float* b1    = (const float*)d_in[4];
    const float* w2    = (const float*)d_in[5];
    const float* b2    = (const float*)d_in[6];
    const float* fcw   = (const float*)d_in[7];
    const float* fcb   = (const float*)d_in[8];
    float* out = (float*)d_out;

    // ---- workspace layout: TOTAL 86,710,528 B (86.7 MB) ----
    // [rbuf 3,541,248][rowidx 4,096][Wt1 28,311,552 | alias: y 8,847,360 + zpart 4,718,592]
    // [Wt2 7,077,888][P 47,775,744]
    char* ws = (char*)d_ws;
    u16*   rbuf  = (u16*)(ws);
    int*   rowidx= (int*)(ws + 3541248);
    u16*   Wt1   = (u16*)(ws + 3545344);
    u16*   y     = (u16*)(ws + 3545344);                    // aliases Wt1 (dead after tapgemm)
    float* zpart = (float*)(ws + 3545344 + 8847360);        // also inside Wt1 region
    u16*   Wt2   = (u16*)(ws + 3545344 + 28311552);
    u16*   P     = (u16*)(ws + 3545344 + 28311552 + 7077888);

    hipLaunchKernelGGL(prep_w_kernel, dim3(512), dim3(256), 1024 * 27 * 2, stream, w1, Wt1, 10);
    hipLaunchKernelGGL(prep_w_kernel, dim3(256), dim3(256), 512 * 27 * 2, stream, w2, Wt2, 9);
    hipLaunchKernelGGL(roi_kernel, dim3(1729), dim3(256), 0, stream, fmaps, boxes, rbuf);
    hipLaunchKernelGGL(rowidx_kernel, dim3(4), dim3(256), 0, stream, pid, rowidx);
    hipLaunchKernelGGL(tapgemm_kernel, dim3(4, 14, 27), dim3(256), 0, stream, Wt1, rbuf, P);
    hipLaunchKernelGGL(reduce_kernel, dim3(8640), dim3(256), 0, stream,
                       (const unsigned*)P, rowidx, b1, (unsigned*)y);
    hipLaunchKernelGGL(gemm2_kernel, dim3(4, 9, 8), dim3(256), 0, stream, Wt2, y, zpart);
    hipLaunchKernelGGL(final_kernel, dim3(192), dim3(256), 0, stream, zpart, b2, fcw, fcb, out);
}

// Round 5
// 383.809 us; speedup vs baseline: 2.0580x; 1.1623x over previous
//
#include <hip/hip_runtime.h>

typedef short s16x8 __attribute__((ext_vector_type(8)));   // 8 bf16 raw bits
typedef float f32x4 __attribute__((ext_vector_type(4)));
typedef unsigned u32x4 __attribute__((ext_vector_type(4)));
typedef unsigned short u16;

__device__ __forceinline__ u16 f2bf(float x){
    unsigned u = __float_as_uint(x);
    unsigned r = u + 0x7fffu + ((u >> 16) & 1u);
    return (u16)(r >> 16);
}
__device__ __forceinline__ float bfhi2f(unsigned v){ return __uint_as_float(v & 0xFFFF0000u); }
__device__ __forceinline__ float bflo2f(unsigned v){ return __uint_as_float(v << 16); }

// async global->LDS, 16B per lane; LDS dest is wave-uniform base + lane*16 (HW), src is per-lane
#define GLOAD_LDS16(g, l) __builtin_amdgcn_global_load_lds( \
        (const __attribute__((address_space(1))) void*)(g), \
        (__attribute__((address_space(3))) void*)(l), 16, 0, 0)

// ---------------- weight prep: in[oc][ic][27] fp32 -> out[oc][tap][C] bf16 -----------------
__global__ void prep_w_kernel(const float* __restrict__ in, u16* __restrict__ out, int icShift){
    extern __shared__ u16 lds[];
    const int C = 1 << icShift;
    const int n = C * 27;
    const int oc = blockIdx.x;
    const float* src = in + (size_t)oc * n;
    for (int i = threadIdx.x; i < n; i += blockDim.x) lds[i] = f2bf(src[i]);
    __syncthreads();
    u16* dst = out + (size_t)oc * n;
    for (int j = threadIdx.x; j < n; j += blockDim.x){
        int tap = j >> icShift;
        int ic  = j & (C - 1);
        dst[j] = lds[ic * 27 + tap];
    }
}

// ---------------- ROI align, LDS-staged: block = (frame, 64-ch chunk) ---------------------
// Loads a contiguous 50 KB chunk of fmaps into LDS (coalesced, read-once), precomputes the
// 54 ROIs' bilinear taps, then samples from LDS. Replaces the 4 B-scatter version that was
// transaction-rate-bound (28 M divergent L2 transactions ~= 82 us).
__global__ __launch_bounds__(256, 2) void roi_kernel(const float* __restrict__ fmaps,
                                                     const float* __restrict__ boxes,
                                                     u16* __restrict__ rbuf){
    __shared__ __align__(16) float planes[12544];   // [64][196] fp32, 50,176 B
    __shared__ int   offsL[54][16];
    __shared__ float wtsL[54][16];
    const int tid = threadIdx.x;
    if (blockIdx.x == 512){                          // zero row 1728
        for (int c = tid; c < 1024; c += 256) rbuf[(size_t)1728 * 1024 + c] = 0;
        return;
    }
    const int f  = blockIdx.x >> 4;
    const int c0 = (blockIdx.x & 15) << 6;

    // 1) coalesced load: 3136 float4 = one contiguous span
    const float4* src = (const float4*)(fmaps + ((size_t)f * 1024 + c0) * 196);
    float4* dl = (float4*)planes;
    for (int i = tid; i < 3136; i += 256) dl[i] = src[i];

    // 2) per-ROI bilinear taps (threads 0..53), 0.25 averaging factor folded into weights
    if (tid < 54){
        const int b = tid / 9, sp = tid % 9;
        const int oh = sp / 3, ow = sp % 3;
        const float* bx = boxes + (f * 6 + b) * 4;
        float x1 = bx[0], y1 = bx[1], x2 = bx[2], y2 = bx[3];
        float bw = fmaxf(x2 - x1, 1.0f) * (1.0f / 3.0f);
        float bh = fmaxf(y2 - y1, 1.0f) * (1.0f / 3.0f);
        int iy0[2], iy1[2], ix0[2], ix1[2];
        float ly[2], lx[2];
#pragma unroll
        for (int s = 0; s < 2; ++s){
            float gy = (float)oh + (s + 0.5f) * 0.5f;
            float ys = y1 + bh * gy;
            float y0f = floorf(ys); y0f = fminf(fmaxf(y0f, 0.f), 13.f);
            ly[s] = fminf(fmaxf(ys - y0f, 0.f), 1.f);
            iy0[s] = (int)y0f; iy1[s] = min(iy0[s] + 1, 13);
            float gx = (float)ow + (s + 0.5f) * 0.5f;
            float xs = x1 + bw * gx;
            float x0f = floorf(xs); x0f = fminf(fmaxf(x0f, 0.f), 13.f);
            lx[s] = fminf(fmaxf(xs - x0f, 0.f), 1.f);
            ix0[s] = (int)x0f; ix1[s] = min(ix0[s] + 1, 13);
        }
        int idx = 0;
#pragma unroll
        for (int sy = 0; sy < 2; ++sy)
#pragma unroll
            for (int sx = 0; sx < 2; ++sx){
                float wy1v = ly[sy], wy0v = 1.f - wy1v;
                float wx1v = lx[sx], wx0v = 1.f - wx1v;
                offsL[tid][idx] = iy0[sy] * 14 + ix0[sx]; wtsL[tid][idx] = wy0v * wx0v * 0.25f; idx++;
                offsL[tid][idx] = iy0[sy] * 14 + ix1[sx]; wtsL[tid][idx] = wy0v * wx1v * 0.25f; idx++;
                offsL[tid][idx] = iy1[sy] * 14 + ix0[sx]; wtsL[tid][idx] = wy1v * wx0v * 0.25f; idx++;
                offsL[tid][idx] = iy1[sy] * 14 + ix1[sx]; wtsL[tid][idx] = wy1v * wx1v * 0.25f; idx++;
            }
    }
    __syncthreads();

    // 3) sample: wave wv owns channels c0+wv*16..+16, lane l = ROI (54 active)
    const int wv = tid >> 6, l = tid & 63;
    if (l < 54){
        int offr[16]; float wtr[16];
#pragma unroll
        for (int i = 0; i < 16; ++i){ offr[i] = offsL[l][i]; wtr[i] = wtsL[l][i]; }
        unsigned pk[8];
#pragma unroll
        for (int jp = 0; jp < 8; ++jp){
            const float* p0 = planes + (wv * 16 + jp * 2) * 196;
            const float* p1 = p0 + 196;
            float a0 = 0.f, a1 = 0.f;
#pragma unroll
            for (int i = 0; i < 16; ++i){
                a0 += p0[offr[i]] * wtr[i];
                a1 += p1[offr[i]] * wtr[i];
            }
            pk[jp] = (unsigned)f2bf(a0) | ((unsigned)f2bf(a1) << 16);
        }
        u16* drow = rbuf + (size_t)(f * 54 + l) * 1024 + c0 + wv * 16;
        *(u32x4*)(drow)     = (u32x4){pk[0], pk[1], pk[2], pk[3]};
        *(u32x4*)(drow + 8) = (u32x4){pk[4], pk[5], pk[6], pk[7]};
    }
}

// ---------------- rowidx[fb][t] = rbuf row base (r*9) of matched person, or -1 ------------
__global__ void rowidx_kernel(const int* __restrict__ pid, int* __restrict__ rowidx){
    int i = blockIdx.x * blockDim.x + threadIdx.x;   // 960 = 192*5
    if (i >= 960) return;
    int fb = i / 5, t = i % 5;
    int f = fb / 6, b = fb % 6;
    int start = max(f - 2, 0);
    int end = min(start + 4, 31);
    int span = end - start;
    int g = start + (t * span) / 4;
    int p = pid[f * 6 + b];
    int r = -1;
#pragma unroll
    for (int j = 0; j < 6; ++j)
        if (pid[g * 6 + j] == p){ r = (g * 6 + j) * 9; break; }
    rowidx[i] = r;
}

// ---------------- stage A: per-tap GEMM  P[tap][mb][r][128] = rbuf[r] . Wt1[oc][tap] ------
// m97 structure: 128x128 tile, BK=64, global_load_lds w16, linear LDS [128][64] u16 with
// XOR bank-swizzle applied as pre-swizzled GLOBAL source + swizzled ds_read (rule #21).
__global__ __launch_bounds__(256, 4) void tapgemm_kernel(
        const u16* __restrict__ Wt1,     // [512][27][1024] bf16
        const u16* __restrict__ rb,      // [1729][1024] bf16 (row 1728 = 0)
        u16* __restrict__ P)             // [27][4][1728][128] bf16 (block-contiguous tiles)
{
    __shared__ u16 lds[16384];           // 32 KB: As [128][64] + Bs [128][64]
    u16* As = lds;
    u16* Bs = lds + 8192;
    const int tid = threadIdx.x;
    const int m0 = blockIdx.x * 128;     // oc
    const int n0 = blockIdx.y * 128;     // r
    const int tap = blockIdx.z;

    // ---- staging geometry: issue (w,j) covers rows w*32+j*8 .. +8 of the 128x64 tile ----
    const int w   = tid >> 6;            // wave
    const int l   = tid & 63;
    const int sub = l >> 3;              // row within 8-row group
    const int csw = (l & 7) ^ sub;       // logical K-chunk for this lane (pre-swizzled source)
    const int rowb = w * 32 + sub;
    const char* gA = (const char*)Wt1 + (size_t)(m0 + rowb) * 55296 + tap * 2048 + csw * 16;
    const char* gB[4];
#pragma unroll
    for (int j = 0; j < 4; ++j){
        int gr = min(n0 + rowb + j * 8, 1728);       // clamp to zero row
        gB[j] = (const char*)rb + (size_t)gr * 2048 + csw * 16;
    }

    const int lane = tid & 63, wv = tid >> 6;
    const int wm = (wv & 1) * 64, wn = (wv >> 1) * 64;
    const int lid = lane & 15, q = lane >> 4;
    const int xr = (lid & 7) << 4;       // read-side swizzle (row&7 == lid&7 for all frags)
    f32x4 acc[4][4];
#pragma unroll
    for (int i = 0; i < 4; ++i)
#pragma unroll
        for (int j = 0; j < 4; ++j) acc[i][j] = (f32x4){0.f, 0.f, 0.f, 0.f};

    for (int kt = 0; kt < 16; ++kt){
        __syncthreads();                 // prior tile fully consumed
#pragma unroll
        for (int j = 0; j < 4; ++j)
            GLOAD_LDS16(gA + (size_t)j * 442368 + kt * 128, &As[(w * 4 + j) * 512]);
#pragma unroll
        for (int j = 0; j < 4; ++j)
            GLOAD_LDS16(gB[j] + kt * 128, &Bs[(w * 4 + j) * 512]);
        __syncthreads();                 // vmcnt drain: staged data visible
#pragma unroll
        for (int ks = 0; ks < 2; ++ks){
            s16x8 af[4], bf[4];
            const int cb = ks * 64 + q * 16;
#pragma unroll
            for (int mi = 0; mi < 4; ++mi)
                af[mi] = *(const s16x8*)((const char*)As + (wm + mi * 16 + lid) * 128 + (cb ^ xr));
#pragma unroll
            for (int ni = 0; ni < 4; ++ni)
                bf[ni] = *(const s16x8*)((const char*)Bs + (wn + ni * 16 + lid) * 128 + (cb ^ xr));
#pragma unroll
            for (int mi = 0; mi < 4; ++mi)
#pragma unroll
                for (int ni = 0; ni < 4; ++ni)
                    acc[mi][ni] = __builtin_amdgcn_mfma_f32_16x16x32_bf16(af[mi], bf[ni], acc[mi][ni], 0, 0, 0);
        }
    }

    // ---- epilogue: LDS-transpose (swizzled, [128 r][256 B]) + contiguous NT writeout ----
    __syncthreads();
#pragma unroll
    for (int mi = 0; mi < 4; ++mi){
        const int colb = (wm + mi * 16 + q * 4) * 2;   // oc-local byte col
#pragma unroll
        for (int ni = 0; ni < 4; ++ni){
            const int row = wn + ni * 16 + lid;        // r-local
            ushort4 o;
            o.x = f2bf(acc[mi][ni][0]);
            o.y = f2bf(acc[mi][ni][1]);
            o.z = f2bf(acc[mi][ni][2]);
            o.w = f2bf(acc[mi][ni][3]);
            *(ushort4*)((char*)lds + row * 256 + (colb ^ xr)) = o;
        }
    }
    __syncthreads();
    // block tile = ONE contiguous 32 KB span of P; stream it out with NT full-line stores
    u16* Pt = P + (((size_t)tap * 4 + blockIdx.x) * 1728 + n0) * 128;
    const int trow = tid >> 4;          // 0..15
    const int c    = tid & 15;          // 16 B chunk within the 256 B row
#pragma unroll
    for (int it = 0; it < 8; ++it){
        const int rl = it * 16 + trow;
        if (n0 + rl < 1728){
            const int pc = (c & 8) | ((c & 7) ^ (rl & 7));
            u32x4 v = *(const u32x4*)((const char*)lds + rl * 256 + pc * 16);
            __builtin_nontemporal_store(v, (u32x4*)(Pt + (size_t)rl * 128 + c * 8));
        }
    }
}

// ---------------- stage B: y[n][oc] = relu(b1 + sum_tap P[tap][mb][src][128]) -------------
__global__ __launch_bounds__(256) void reduce_kernel(
        const unsigned* __restrict__ P32,   // [27][4][1728][64] (u32 = 2 bf16)
        const int* __restrict__ rowidx,     // [192][5]
        const float* __restrict__ b1,       // [512]
        unsigned* __restrict__ y32)         // [8640][256]
{
    __shared__ int rows[27];
    const int n = blockIdx.x;             // 0..8639
    const int tid = threadIdx.x;
    const int fb = n / 45, rr = n % 45;
    const int od = rr / 9, oh = (rr % 9) / 3, ow = rr % 3;
    if (tid < 27){
        int kd = tid / 9, kh = (tid % 9) / 3, kw = tid % 3;
        int t = od + kd - 1, h = oh + kh - 1, w = ow + kw - 1;
        int row = -1;
        if ((unsigned)t < 5u && (unsigned)h < 3u && (unsigned)w < 3u){
            int rbv = rowidx[fb * 5 + t];
            if (rbv >= 0) row = rbv + h * 3 + w;
        }
        rows[tid] = row;
    }
    __syncthreads();
    const int mb = tid >> 6;              // oc-block of this thread's u32 pair
    const int lc = tid & 63;
    float a0 = 0.f, a1 = 0.f;
#pragma unroll
    for (int tap = 0; tap < 27; ++tap){
        int r = rows[tap];
        if (r >= 0){
            unsigned v = P32[(((size_t)tap * 4 + mb) * 1728 + r) * 64 + lc];
            a0 += bflo2f(v);
            a1 += bfhi2f(v);
        }
    }
    a0 = fmaxf(a0 + b1[tid * 2], 0.f);
    a1 = fmaxf(a1 + b1[tid * 2 + 1], 0.f);
    y32[(size_t)n * 256 + tid] = (unsigned)f2bf(a0) | ((unsigned)f2bf(a1) << 16);
}

// ---------------- GEMM2: conv1b, 64x64 tile, BK=64, split-K=8 -----------------------------
#define KP1 72   // LDS row stride (u16)

__global__ __launch_bounds__(256) void gemm2_kernel(
        const u16* __restrict__ Wt2,   // [256][13824] bf16, k = tap*512+ic
        const u16* __restrict__ y,     // [8640][512] bf16; row n=fb*45+od*9+sp
        float* __restrict__ zpart)     // [8][576][256]
{
    __shared__ u16 As[64 * KP1];
    __shared__ u16 Bs[64 * KP1];
    const int tid = threadIdx.x;
    const int m0 = blockIdx.x * 64;
    const int n0 = blockIdx.y * 64;
    const int kz = blockIdx.z;
    const int kbase = kz * 1728;            // 27 chunks of 64
    const int arow = tid >> 2, seg = tid & 3;
    const u16* aptr = Wt2 + (size_t)(m0 + arow) * 13824 + kbase + seg * 16;
    const int n2 = n0 + arow;
    const int fb = n2 / 3, od2 = n2 - fb * 3;
    const u16* bptr = y + (size_t)(fb * 45 + od2 * 9) * 512 + kbase + seg * 16;

    const int lane = tid & 63, wv = tid >> 6;
    const int wm = (wv & 1) * 32, wn = (wv >> 1) * 32;
    const int lid = lane & 15, q = lane >> 4;
    f32x4 acc[2][2];
#pragma unroll
    for (int i = 0; i < 2; ++i)
#pragma unroll
        for (int j = 0; j < 2; ++j) acc[i][j] = (f32x4){0.f, 0.f, 0.f, 0.f};

    uint4 aC[2], bC[2], aN[2], bN[2];
#pragma unroll
    for (int j = 0; j < 2; ++j){
        aC[j] = *(const uint4*)(aptr + j * 8);
        bC[j] = *(const uint4*)(bptr + j * 8);
    }
    for (int kt = 0; kt < 27; ++kt){
        __syncthreads();
        {
            u16* as = &As[arow * KP1 + seg * 16];
            u16* bs = &Bs[arow * KP1 + seg * 16];
#pragma unroll
            for (int j = 0; j < 2; ++j){
                *(uint4*)(as + j * 8) = aC[j];
                *(uint4*)(bs + j * 8) = bC[j];
            }
        }
        __syncthreads();
        if (kt + 1 < 27){
            const u16* ap = aptr + (kt + 1) * 64;
            const u16* bp = bptr + (kt + 1) * 64;
#pragma unroll
            for (int j = 0; j < 2; ++j){
                aN[j] = *(const uint4*)(ap + j * 8);
                bN[j] = *(const uint4*)(bp + j * 8);
            }
        }
#pragma unroll
        for (int ks = 0; ks < 2; ++ks){
            s16x8 af[2], bf[2];
#pragma unroll
            for (int mi = 0; mi < 2; ++mi) af[mi] = *(const s16x8*)&As[(wm + mi * 16 + lid) * KP1 + ks * 32 + q * 8];
#pragma unroll
            for (int ni = 0; ni < 2; ++ni) bf[ni] = *(const s16x8*)&Bs[(wn + ni * 16 + lid) * KP1 + ks * 32 + q * 8];
#pragma unroll
            for (int mi = 0; mi < 2; ++mi)
#pragma unroll
                for (int ni = 0; ni < 2; ++ni)
                    acc[mi][ni] = __builtin_amdgcn_mfma_f32_16x16x32_bf16(af[mi], bf[ni], acc[mi][ni], 0, 0, 0);
        }
#pragma unroll
        for (int j = 0; j < 2; ++j){ aC[j] = aN[j]; bC[j] = bN[j]; }
    }
#pragma unroll
    for (int mi = 0; mi < 2; ++mi){
        const int mbase = m0 + wm + mi * 16 + q * 4;
#pragma unroll
        for (int ni = 0; ni < 2; ++ni){
            const int n = n0 + wn + ni * 16 + lid;
            float4 o = make_float4(acc[mi][ni][0], acc[mi][ni][1], acc[mi][ni][2], acc[mi][ni][3]);
            *(float4*)(zpart + ((size_t)kz * 576 + n) * 256 + mbase) = o;
        }
    }
}

// ---------------- final: sum split-K + bias + relu + max over D + FC 256->27 (fp32 out) ----
__global__ __launch_bounds__(256) void final_kernel(
        const float* __restrict__ zpart, const float* __restrict__ b2,
        const float* __restrict__ fcw, const float* __restrict__ fcb,
        float* __restrict__ out){
    __shared__ float smv[256];
    const int fb = blockIdx.x, tid = threadIdx.x;
    const float bias = b2[tid];
    float mv = 0.f;
#pragma unroll
    for (int od = 0; od < 3; ++od){
        const int n = fb * 3 + od;
        float s = 0.f;
#pragma unroll
        for (int sp = 0; sp < 8; ++sp) s += zpart[((size_t)sp * 576 + n) * 256 + tid];
        s = fmaxf(s + bias, 0.f);
        mv = fmaxf(mv, s);
    }
    smv[tid] = mv;
    __syncthreads();
    const int wv = tid >> 6, lane = tid & 63;
    for (int cls = wv; cls < 27; cls += 4){
        const float* wrow = fcw + cls * 256;
        float s = 0.f;
#pragma unroll
        for (int j = 0; j < 4; ++j) s += smv[lane + j * 64] * wrow[lane + j * 64];
#pragma unroll
        for (int off = 32; off > 0; off >>= 1) s += __shfl_xor(s, off);
        if (lane == 0) out[fb * 27 + cls] = s + fcb[cls];
    }
}

extern "C" void kernel_launch(void* const* d_in, const int* in_sizes, int n_in,
                              void* d_out, int out_size, void* d_ws, size_t ws_size,
                              hipStream_t stream){
    const float* fmaps = (const float*)d_in[0];
    const float* boxes = (const float*)d_in[1];
    const int*   pid   = (const int*)d_in[2];
    const float* w1    = (const float*)d_in[3];
    const float* b1    = (const float*)d_in[4];
    const float* w2    = (const float*)d_in[5];
    const float* b2    = (const float*)d_in[6];
    const float* fcw   = (const float*)d_in[7];
    const float* fcb   = (const float*)d_in[8];
    float* out = (float*)d_out;

    // ---- workspace layout: TOTAL 86,710,528 B (86.7 MB) ----
    // [rbuf 3,541,248][rowidx 4,096][Wt1 28,311,552 | alias: y 8,847,360 + zpart 4,718,592]
    // [Wt2 7,077,888][P 47,775,744]
    char* ws = (char*)d_ws;
    u16*   rbuf  = (u16*)(ws);
    int*   rowidx= (int*)(ws + 3541248);
    u16*   Wt1   = (u16*)(ws + 3545344);
    u16*   y     = (u16*)(ws + 3545344);                    // aliases Wt1 (dead after tapgemm)
    float* zpart = (float*)(ws + 3545344 + 8847360);        // also inside Wt1 region
    u16*   Wt2   = (u16*)(ws + 3545344 + 28311552);
    u16*   P     = (u16*)(ws + 3545344 + 28311552 + 7077888);

    hipLaunchKernelGGL(prep_w_kernel, dim3(512), dim3(256), 1024 * 27 * 2, stream, w1, Wt1, 10);
    hipLaunchKernelGGL(prep_w_kernel, dim3(256), dim3(256), 512 * 27 * 2, stream, w2, Wt2, 9);
    hipLaunchKernelGGL(roi_kernel, dim3(513), dim3(256), 0, stream, fmaps, boxes, rbuf);
    hipLaunchKernelGGL(rowidx_kernel, dim3(4), dim3(256), 0, stream, pid, rowidx);
    hipLaunchKernelGGL(tapgemm_kernel, dim3(4, 14, 27), dim3(256), 0, stream, Wt1, rbuf, P);
    hipLaunchKernelGGL(reduce_kernel, dim3(8640), dim3(256), 0, stream,
                       (const unsigned*)P, rowidx, b1, (unsigned*)y);
    hipLaunchKernelGGL(gemm2_kernel, dim3(4, 9, 8), dim3(256), 0, stream, Wt2, y, zpart);
    hipLaunchKernelGGL(final_kernel, dim3(192), dim3(256), 0, stream, zpart, b2, fcw, fcb, out);
}

// Round 6
// 351.324 us; speedup vs baseline: 2.2483x; 1.0925x over previous
//
#include <hip/hip_runtime.h>

typedef short s16x8 __attribute__((ext_vector_type(8)));   // 8 bf16 raw bits
typedef float f32x4 __attribute__((ext_vector_type(4)));
typedef unsigned u32x4 __attribute__((ext_vector_type(4)));
typedef unsigned short u16;

__device__ __forceinline__ u16 f2bf(float x){
    unsigned u = __float_as_uint(x);
    unsigned r = u + 0x7fffu + ((u >> 16) & 1u);
    return (u16)(r >> 16);
}
__device__ __forceinline__ float bfhi2f(unsigned v){ return __uint_as_float(v & 0xFFFF0000u); }
__device__ __forceinline__ float bflo2f(unsigned v){ return __uint_as_float(v << 16); }

// async global->LDS, 16B per lane; LDS dest is wave-uniform base + lane*16 (HW), src is per-lane
#define GLOAD_LDS16(g, l) __builtin_amdgcn_global_load_lds( \
        (const __attribute__((address_space(1))) void*)(g), \
        (__attribute__((address_space(3))) void*)(l), 16, 0, 0)

// ---------------- weight prep: in[oc][ic][27] fp32 -> out[oc][tap][C] bf16 -----------------
__global__ void prep_w_kernel(const float* __restrict__ in, u16* __restrict__ out, int icShift){
    extern __shared__ u16 lds[];
    const int C = 1 << icShift;
    const int n = C * 27;
    const int oc = blockIdx.x;
    const float* src = in + (size_t)oc * n;
    for (int i = threadIdx.x; i < n; i += blockDim.x) lds[i] = f2bf(src[i]);
    __syncthreads();
    u16* dst = out + (size_t)oc * n;
    for (int j = threadIdx.x; j < n; j += blockDim.x){
        int tap = j >> icShift;
        int ic  = j & (C - 1);
        dst[j] = lds[ic * 27 + tap];
    }
}

// ---------------- ROI align, LDS-staged: block = (frame, 64-ch chunk) ---------------------
__global__ __launch_bounds__(256, 2) void roi_kernel(const float* __restrict__ fmaps,
                                                     const float* __restrict__ boxes,
                                                     u16* __restrict__ rbuf){
    __shared__ __align__(16) float planes[12544];   // [64][196] fp32, 50,176 B
    __shared__ int   offsL[54][16];
    __shared__ float wtsL[54][16];
    const int tid = threadIdx.x;
    if (blockIdx.x == 512){                          // zero row 1728
        for (int c = tid; c < 1024; c += 256) rbuf[(size_t)1728 * 1024 + c] = 0;
        return;
    }
    const int f  = blockIdx.x >> 4;
    const int c0 = (blockIdx.x & 15) << 6;

    // 1) coalesced load: 3136 float4 = one contiguous span
    const float4* src = (const float4*)(fmaps + ((size_t)f * 1024 + c0) * 196);
    float4* dl = (float4*)planes;
    for (int i = tid; i < 3136; i += 256) dl[i] = src[i];

    // 2) per-ROI bilinear taps (threads 0..53), 0.25 averaging factor folded into weights
    if (tid < 54){
        const int b = tid / 9, sp = tid % 9;
        const int oh = sp / 3, ow = sp % 3;
        const float* bx = boxes + (f * 6 + b) * 4;
        float x1 = bx[0], y1 = bx[1], x2 = bx[2], y2 = bx[3];
        float bw = fmaxf(x2 - x1, 1.0f) * (1.0f / 3.0f);
        float bh = fmaxf(y2 - y1, 1.0f) * (1.0f / 3.0f);
        int iy0[2], iy1[2], ix0[2], ix1[2];
        float ly[2], lx[2];
#pragma unroll
        for (int s = 0; s < 2; ++s){
            float gy = (float)oh + (s + 0.5f) * 0.5f;
            float ys = y1 + bh * gy;
            float y0f = floorf(ys); y0f = fminf(fmaxf(y0f, 0.f), 13.f);
            ly[s] = fminf(fmaxf(ys - y0f, 0.f), 1.f);
            iy0[s] = (int)y0f; iy1[s] = min(iy0[s] + 1, 13);
            float gx = (float)ow + (s + 0.5f) * 0.5f;
            float xs = x1 + bw * gx;
            float x0f = floorf(xs); x0f = fminf(fmaxf(x0f, 0.f), 13.f);
            lx[s] = fminf(fmaxf(xs - x0f, 0.f), 1.f);
            ix0[s] = (int)x0f; ix1[s] = min(ix0[s] + 1, 13);
        }
        int idx = 0;
#pragma unroll
        for (int sy = 0; sy < 2; ++sy)
#pragma unroll
            for (int sx = 0; sx < 2; ++sx){
                float wy1v = ly[sy], wy0v = 1.f - wy1v;
                float wx1v = lx[sx], wx0v = 1.f - wx1v;
                offsL[tid][idx] = iy0[sy] * 14 + ix0[sx]; wtsL[tid][idx] = wy0v * wx0v * 0.25f; idx++;
                offsL[tid][idx] = iy0[sy] * 14 + ix1[sx]; wtsL[tid][idx] = wy0v * wx1v * 0.25f; idx++;
                offsL[tid][idx] = iy1[sy] * 14 + ix0[sx]; wtsL[tid][idx] = wy1v * wx0v * 0.25f; idx++;
                offsL[tid][idx] = iy1[sy] * 14 + ix1[sx]; wtsL[tid][idx] = wy1v * wx1v * 0.25f; idx++;
            }
    }
    __syncthreads();

    // 3) sample: wave wv owns channels c0+wv*16..+16, lane l = ROI (54 active)
    const int wv = tid >> 6, l = tid & 63;
    if (l < 54){
        int offr[16]; float wtr[16];
#pragma unroll
        for (int i = 0; i < 16; ++i){ offr[i] = offsL[l][i]; wtr[i] = wtsL[l][i]; }
        unsigned pk[8];
#pragma unroll
        for (int jp = 0; jp < 8; ++jp){
            const float* p0 = planes + (wv * 16 + jp * 2) * 196;
            const float* p1 = p0 + 196;
            float a0 = 0.f, a1 = 0.f;
#pragma unroll
            for (int i = 0; i < 16; ++i){
                a0 += p0[offr[i]] * wtr[i];
                a1 += p1[offr[i]] * wtr[i];
            }
            pk[jp] = (unsigned)f2bf(a0) | ((unsigned)f2bf(a1) << 16);
        }
        u16* drow = rbuf + (size_t)(f * 54 + l) * 1024 + c0 + wv * 16;
        *(u32x4*)(drow)     = (u32x4){pk[0], pk[1], pk[2], pk[3]};
        *(u32x4*)(drow + 8) = (u32x4){pk[4], pk[5], pk[6], pk[7]};
    }
}

// ---------------- rowidx[fb][t] = rbuf row base (r*9) of matched person, or -1 ------------
__global__ void rowidx_kernel(const int* __restrict__ pid, int* __restrict__ rowidx){
    int i = blockIdx.x * blockDim.x + threadIdx.x;   // 960 = 192*5
    if (i >= 960) return;
    int fb = i / 5, t = i % 5;
    int f = fb / 6, b = fb % 6;
    int start = max(f - 2, 0);
    int end = min(start + 4, 31);
    int span = end - start;
    int g = start + (t * span) / 4;
    int p = pid[f * 6 + b];
    int r = -1;
#pragma unroll
    for (int j = 0; j < 6; ++j)
        if (pid[g * 6 + j] == p){ r = (g * 6 + j) * 9; break; }
    rowidx[i] = r;
}

// ---------------- stage A: per-tap GEMM  P[tap][mb][r][128] = rbuf[r] . Wt1[oc][tap] ------
// m97 structure: 128x128 tile, BK=64, global_load_lds w16, linear LDS [128][64] u16 with
// XOR bank-swizzle applied as pre-swizzled GLOBAL source + swizzled ds_read (rule #21).
__global__ __launch_bounds__(256, 4) void tapgemm_kernel(
        const u16* __restrict__ Wt1,     // [512][27][1024] bf16
        const u16* __restrict__ rb,      // [1729][1024] bf16 (row 1728 = 0)
        u16* __restrict__ P)             // [27][4][1728][128] bf16 (block-contiguous tiles)
{
    __shared__ u16 lds[16384];           // 32 KB: As [128][64] + Bs [128][64]
    u16* As = lds;
    u16* Bs = lds + 8192;
    const int tid = threadIdx.x;
    const int m0 = blockIdx.x * 128;     // oc
    const int n0 = blockIdx.y * 128;     // r
    const int tap = blockIdx.z;

    // ---- staging geometry: issue (w,j) covers rows w*32+j*8 .. +8 of the 128x64 tile ----
    const int w   = tid >> 6;            // wave
    const int l   = tid & 63;
    const int sub = l >> 3;              // row within 8-row group
    const int csw = (l & 7) ^ sub;       // logical K-chunk for this lane (pre-swizzled source)
    const int rowb = w * 32 + sub;
    const char* gA = (const char*)Wt1 + (size_t)(m0 + rowb) * 55296 + tap * 2048 + csw * 16;
    const char* gB[4];
#pragma unroll
    for (int j = 0; j < 4; ++j){
        int gr = min(n0 + rowb + j * 8, 1728);       // clamp to zero row
        gB[j] = (const char*)rb + (size_t)gr * 2048 + csw * 16;
    }

    const int lane = tid & 63, wv = tid >> 6;
    const int wm = (wv & 1) * 64, wn = (wv >> 1) * 64;
    const int lid = lane & 15, q = lane >> 4;
    const int xr = (lid & 7) << 4;       // read-side swizzle (row&7 == lid&7 for all frags)
    f32x4 acc[4][4];
#pragma unroll
    for (int i = 0; i < 4; ++i)
#pragma unroll
        for (int j = 0; j < 4; ++j) acc[i][j] = (f32x4){0.f, 0.f, 0.f, 0.f};

    for (int kt = 0; kt < 16; ++kt){
        __syncthreads();                 // prior tile fully consumed
#pragma unroll
        for (int j = 0; j < 4; ++j)
            GLOAD_LDS16(gA + (size_t)j * 442368 + kt * 128, &As[(w * 4 + j) * 512]);
#pragma unroll
        for (int j = 0; j < 4; ++j)
            GLOAD_LDS16(gB[j] + kt * 128, &Bs[(w * 4 + j) * 512]);
        __syncthreads();                 // vmcnt drain: staged data visible
#pragma unroll
        for (int ks = 0; ks < 2; ++ks){
            s16x8 af[4], bf[4];
            const int cb = ks * 64 + q * 16;
#pragma unroll
            for (int mi = 0; mi < 4; ++mi)
                af[mi] = *(const s16x8*)((const char*)As + (wm + mi * 16 + lid) * 128 + (cb ^ xr));
#pragma unroll
            for (int ni = 0; ni < 4; ++ni)
                bf[ni] = *(const s16x8*)((const char*)Bs + (wn + ni * 16 + lid) * 128 + (cb ^ xr));
#pragma unroll
            for (int mi = 0; mi < 4; ++mi)
#pragma unroll
                for (int ni = 0; ni < 4; ++ni)
                    acc[mi][ni] = __builtin_amdgcn_mfma_f32_16x16x32_bf16(af[mi], bf[ni], acc[mi][ni], 0, 0, 0);
        }
    }

    // ---- epilogue: LDS-transpose (swizzled, [128 r][256 B]) + contiguous NT writeout ----
    __syncthreads();
#pragma unroll
    for (int mi = 0; mi < 4; ++mi){
        const int colb = (wm + mi * 16 + q * 4) * 2;   // oc-local byte col
#pragma unroll
        for (int ni = 0; ni < 4; ++ni){
            const int row = wn + ni * 16 + lid;        // r-local
            ushort4 o;
            o.x = f2bf(acc[mi][ni][0]);
            o.y = f2bf(acc[mi][ni][1]);
            o.z = f2bf(acc[mi][ni][2]);
            o.w = f2bf(acc[mi][ni][3]);
            *(ushort4*)((char*)lds + row * 256 + (colb ^ xr)) = o;
        }
    }
    __syncthreads();
    // block tile = ONE contiguous 32 KB span of P; stream it out with NT full-line stores
    u16* Pt = P + (((size_t)tap * 4 + blockIdx.x) * 1728 + n0) * 128;
    const int trow = tid >> 4;          // 0..15
    const int c    = tid & 15;          // 16 B chunk within the 256 B row
#pragma unroll
    for (int it = 0; it < 8; ++it){
        const int rl = it * 16 + trow;
        if (n0 + rl < 1728){
            const int pc = (c & 8) | ((c & 7) ^ (rl & 7));
            u32x4 v = *(const u32x4*)((const char*)lds + rl * 256 + pc * 16);
            __builtin_nontemporal_store(v, (u32x4*)(Pt + (size_t)rl * 128 + c * 8));
        }
    }
}

// ---------------- stage B: y[n][oc] = relu(b1 + sum_tap P[tap][mb][src][128]) -------------
__global__ __launch_bounds__(256) void reduce_kernel(
        const unsigned* __restrict__ P32,   // [27][4][1728][64] (u32 = 2 bf16)
        const int* __restrict__ rowidx,     // [192][5]
        const float* __restrict__ b1,       // [512]
        unsigned* __restrict__ y32)         // [8640][256]
{
    __shared__ int rows[27];
    const int n = blockIdx.x;             // 0..8639
    const int tid = threadIdx.x;
    const int fb = n / 45, rr = n % 45;
    const int od = rr / 9, oh = (rr % 9) / 3, ow = rr % 3;
    if (tid < 27){
        int kd = tid / 9, kh = (tid % 9) / 3, kw = tid % 3;
        int t = od + kd - 1, h = oh + kh - 1, w = ow + kw - 1;
        int row = -1;
        if ((unsigned)t < 5u && (unsigned)h < 3u && (unsigned)w < 3u){
            int rbv = rowidx[fb * 5 + t];
            if (rbv >= 0) row = rbv + h * 3 + w;
        }
        rows[tid] = row;
    }
    __syncthreads();
    const int mb = tid >> 6;              // oc-block of this thread's u32 pair
    const int lc = tid & 63;
    float a0 = 0.f, a1 = 0.f;
#pragma unroll
    for (int tap = 0; tap < 27; ++tap){
        int r = rows[tap];
        if (r >= 0){
            unsigned v = P32[(((size_t)tap * 4 + mb) * 1728 + r) * 64 + lc];
            a0 += bflo2f(v);
            a1 += bfhi2f(v);
        }
    }
    a0 = fmaxf(a0 + b1[tid * 2], 0.f);
    a1 = fmaxf(a1 + b1[tid * 2 + 1], 0.f);
    y32[(size_t)n * 256 + tid] = (unsigned)f2bf(a0) | ((unsigned)f2bf(a1) << 16);
}

// ---------------- GEMM2: conv1b, 64x64 tile, BK=64, split-K=27 (one tap per split) --------
// m97 structure (same as tapgemm, 64-row variant): global_load_lds w16 + swizzle pair.
// zpart is block-contiguous [27][4][576][64] f32, streamed with NT full-line stores.
__global__ __launch_bounds__(256, 4) void gemm2_kernel(
        const u16* __restrict__ Wt2,   // [256][13824] bf16, k = tap*512+ic
        const u16* __restrict__ y,     // [8640][512] bf16; row n=fb*45+od*9+sp
        float* __restrict__ zpart)     // [27][4][576][64] f32
{
    __shared__ u16 lds[8192];          // 16 KB: As [64][64] + Bs [64][64] u16
    u16* As = lds;
    u16* Bs = lds + 4096;
    const int tid = threadIdx.x;
    const int m0 = blockIdx.x * 64;    // oc2
    const int n0 = blockIdx.y * 64;    // n (fb*3+od)
    const int kz = blockIdx.z;         // tap 0..26

    // staging geometry: wave w, issue j covers rows w*16+j*8..+8 of the 64x64 tile
    const int w   = tid >> 6;
    const int l   = tid & 63;
    const int sub = l >> 3;
    const int csw = (l & 7) ^ sub;     // pre-swizzled source K-chunk
    const int rowb = w * 16 + sub;
    const char* gA = (const char*)Wt2 + (size_t)(m0 + rowb) * 27648 + kz * 1024 + csw * 16;
    const char* gB[2];
#pragma unroll
    for (int j = 0; j < 2; ++j){
        const int n2 = n0 + rowb + j * 8;
        const int fb = n2 / 3, od2 = n2 - fb * 3;
        gB[j] = (const char*)y + ((size_t)(fb * 45 + od2 * 9) + kz) * 1024 + csw * 16;
    }

    const int lane = tid & 63, wv = tid >> 6;
    const int wm = (wv & 1) * 32, wn = (wv >> 1) * 32;
    const int lid = lane & 15, q = lane >> 4;
    const int xr = (lid & 7) << 4;
    f32x4 acc[2][2];
#pragma unroll
    for (int i = 0; i < 2; ++i)
#pragma unroll
        for (int j = 0; j < 2; ++j) acc[i][j] = (f32x4){0.f, 0.f, 0.f, 0.f};

    for (int kt = 0; kt < 8; ++kt){
        __syncthreads();
#pragma unroll
        for (int j = 0; j < 2; ++j)
            GLOAD_LDS16(gA + (size_t)j * 221184 + kt * 128, &As[(w * 2 + j) * 512]);
#pragma unroll
        for (int j = 0; j < 2; ++j)
            GLOAD_LDS16(gB[j] + kt * 128, &Bs[(w * 2 + j) * 512]);
        __syncthreads();
#pragma unroll
        for (int ks = 0; ks < 2; ++ks){
            s16x8 af[2], bf[2];
            const int cb = ks * 64 + q * 16;
#pragma unroll
            for (int mi = 0; mi < 2; ++mi)
                af[mi] = *(const s16x8*)((const char*)As + (wm + mi * 16 + lid) * 128 + (cb ^ xr));
#pragma unroll
            for (int ni = 0; ni < 2; ++ni)
                bf[ni] = *(const s16x8*)((const char*)Bs + (wn + ni * 16 + lid) * 128 + (cb ^ xr));
#pragma unroll
            for (int mi = 0; mi < 2; ++mi)
#pragma unroll
                for (int ni = 0; ni < 2; ++ni)
                    acc[mi][ni] = __builtin_amdgcn_mfma_f32_16x16x32_bf16(af[mi], bf[ni], acc[mi][ni], 0, 0, 0);
        }
    }

    // ---- epilogue: stage f32 tile [64 n][64 oc] in LDS (swizzled) + contiguous NT out ----
    __syncthreads();
#pragma unroll
    for (int mi = 0; mi < 2; ++mi){
        const int colb = (wm + mi * 16 + q * 4) * 4;   // oc-local byte col (f32)
#pragma unroll
        for (int ni = 0; ni < 2; ++ni){
            const int row = wn + ni * 16 + lid;        // n-local
            *(f32x4*)((char*)lds + row * 256 + (colb ^ xr)) = acc[mi][ni];
        }
    }
    __syncthreads();
    float* zb = zpart + (((size_t)kz * 4 + blockIdx.x) * 576 + n0) * 64;
    const int trow = tid >> 4;          // 0..15
    const int c    = tid & 15;          // 16 B chunk within the 256 B row
#pragma unroll
    for (int it = 0; it < 4; ++it){
        const int rl = it * 16 + trow;
        const int pc = (c & 8) | ((c & 7) ^ (rl & 7));
        u32x4 v = *(const u32x4*)((const char*)lds + rl * 256 + pc * 16);
        __builtin_nontemporal_store(v, (u32x4*)(zb + (size_t)rl * 64 + c * 4));
    }
}

// ---------------- final: sum split-K + bias + relu + max over D + FC 256->27 (fp32 out) ----
__global__ __launch_bounds__(256) void final_kernel(
        const float* __restrict__ zpart,   // [27][4][576][64]
        const float* __restrict__ b2,
        const float* __restrict__ fcw, const float* __restrict__ fcb,
        float* __restrict__ out){
    __shared__ float smv[256];
    const int fb = blockIdx.x, tid = threadIdx.x;
    const int mb = tid >> 6, c = tid & 63;       // oc = mb*64 + c = tid
    const float bias = b2[tid];
    float mv = 0.f;
#pragma unroll
    for (int od = 0; od < 3; ++od){
        const int n = fb * 3 + od;
        float s = 0.f;
#pragma unroll
        for (int kz = 0; kz < 27; ++kz)
            s += zpart[(((size_t)kz * 4 + mb) * 576 + n) * 64 + c];
        s = fmaxf(s + bias, 0.f);
        mv = fmaxf(mv, s);
    }
    smv[tid] = mv;
    __syncthreads();
    const int wv = tid >> 6, lane = tid & 63;
    for (int cls = wv; cls < 27; cls += 4){
        const float* wrow = fcw + cls * 256;
        float s = 0.f;
#pragma unroll
        for (int j = 0; j < 4; ++j) s += smv[lane + j * 64] * wrow[lane + j * 64];
#pragma unroll
        for (int off = 32; off > 0; off >>= 1) s += __shfl_xor(s, off);
        if (lane == 0) out[fb * 27 + cls] = s + fcb[cls];
    }
}

extern "C" void kernel_launch(void* const* d_in, const int* in_sizes, int n_in,
                              void* d_out, int out_size, void* d_ws, size_t ws_size,
                              hipStream_t stream){
    const float* fmaps = (const float*)d_in[0];
    const float* boxes = (const float*)d_in[1];
    const int*   pid   = (const int*)d_in[2];
    const float* w1    = (const float*)d_in[3];
    const float* b1    = (const float*)d_in[4];
    const float* w2    = (const float*)d_in[5];
    const float* b2    = (const float*)d_in[6];
    const float* fcw   = (const float*)d_in[7];
    const float* fcb   = (const float*)d_in[8];
    float* out = (float*)d_out;

    // ---- workspace layout: TOTAL 86,710,528 B (86.7 MB) ----
    // [rbuf 3,541,248][rowidx 4,096][Wt1 28,311,552 | alias: y 8,847,360 + zpart 15,925,248]
    // [Wt2 7,077,888][P 47,775,744]
    char* ws = (char*)d_ws;
    u16*   rbuf  = (u16*)(ws);
    int*   rowidx= (int*)(ws + 3541248);
    u16*   Wt1   = (u16*)(ws + 3545344);
    u16*   y     = (u16*)(ws + 3545344);                    // aliases Wt1 (dead after tapgemm)
    float* zpart = (float*)(ws + 3545344 + 8847360);        // also inside Wt1 region (24.8 MB used of 28.3)
    u16*   Wt2   = (u16*)(ws + 3545344 + 28311552);
    u16*   P     = (u16*)(ws + 3545344 + 28311552 + 7077888);

    hipLaunchKernelGGL(prep_w_kernel, dim3(512), dim3(256), 1024 * 27 * 2, stream, w1, Wt1, 10);
    hipLaunchKernelGGL(prep_w_kernel, dim3(256), dim3(256), 512 * 27 * 2, stream, w2, Wt2, 9);
    hipLaunchKernelGGL(roi_kernel, dim3(513), dim3(256), 0, stream, fmaps, boxes, rbuf);
    hipLaunchKernelGGL(rowidx_kernel, dim3(4), dim3(256), 0, stream, pid, rowidx);
    hipLaunchKernelGGL(tapgemm_kernel, dim3(4, 14, 27), dim3(256), 0, stream, Wt1, rbuf, P);
    hipLaunchKernelGGL(reduce_kernel, dim3(8640), dim3(256), 0, stream,
                       (const unsigned*)P, rowidx, b1, (unsigned*)y);
    hipLaunchKernelGGL(gemm2_kernel, dim3(4, 9, 27), dim3(256), 0, stream, Wt2, y, zpart);
    hipLaunchKernelGGL(final_kernel, dim3(192), dim3(256), 0, stream, zpart, b2, fcw, fcb, out);
}

// Round 7
// 283.026 us; speedup vs baseline: 2.7908x; 1.2413x over previous
//
#include <hip/hip_runtime.h>

typedef short s16x8 __attribute__((ext_vector_type(8)));   // 8 bf16 raw bits
typedef float f32x4 __attribute__((ext_vector_type(4)));
typedef unsigned u32x4 __attribute__((ext_vector_type(4)));
typedef unsigned short u16;

__device__ __forceinline__ u16 f2bf(float x){
    unsigned u = __float_as_uint(x);
    unsigned r = u + 0x7fffu + ((u >> 16) & 1u);
    return (u16)(r >> 16);
}
__device__ __forceinline__ float bfhi2f(unsigned v){ return __uint_as_float(v & 0xFFFF0000u); }
__device__ __forceinline__ float bflo2f(unsigned v){ return __uint_as_float(v << 16); }

// async global->LDS, 16B per lane; LDS dest is wave-uniform base + lane*16 (HW), src is per-lane
#define GLOAD_LDS16(g, l) __builtin_amdgcn_global_load_lds( \
        (const __attribute__((address_space(1))) void*)(g), \
        (__attribute__((address_space(3))) void*)(l), 16, 0, 0)

// ---------------- weight prep: in[oc][ic][27] fp32 -> out[oc][tap][C] bf16 -----------------
// Vectorized (float4 in / ushort4 out) + oc split into ic-halves for occupancy.
// Old version had VGPR_Count=4 -> one load in flight -> latency-serialized (68 us).
__global__ __launch_bounds__(256) void prep_w_kernel(const float* __restrict__ in,
                                                     u16* __restrict__ out,
                                                     int cbShift, int CShift){
    extern __shared__ u16 lds[];                       // [Cb][27] u16, linear
    const int Cb = 1 << cbShift;                       // ic handled by this block
    const int C  = 1 << CShift;
    const int splitShift = CShift - cbShift;
    const int oc  = blockIdx.x >> splitShift;
    const int ic0 = (blockIdx.x & ((1 << splitShift) - 1)) << cbShift;
    const int n4 = (27 << cbShift) >> 2;               // float4 count
    const int tid = threadIdx.x;

    const float4* src = (const float4*)(in + ((size_t)oc * C + ic0) * 27);
#pragma unroll 4
    for (int i = tid; i < n4; i += 256){
        float4 v = src[i];
        ushort4 o;
        o.x = f2bf(v.x); o.y = f2bf(v.y); o.z = f2bf(v.z); o.w = f2bf(v.w);
        *(ushort4*)&lds[i * 4] = o;
    }
    __syncthreads();
    u16* dst = out + (size_t)oc * 27 * C + ic0;
#pragma unroll 4
    for (int j = tid; j < n4; j += 256){
        const int jj  = j << 2;
        const int tap = jj >> cbShift;
        const int icl = jj & (Cb - 1);
        ushort4 o;
        o.x = lds[(icl    ) * 27 + tap];
        o.y = lds[(icl + 1) * 27 + tap];
        o.z = lds[(icl + 2) * 27 + tap];
        o.w = lds[(icl + 3) * 27 + tap];
        *(ushort4*)(dst + (size_t)tap * C + icl) = o;
    }
}

// ---------------- ROI align, LDS-staged: block = (frame, 64-ch chunk) ---------------------
__global__ __launch_bounds__(256, 2) void roi_kernel(const float* __restrict__ fmaps,
                                                     const float* __restrict__ boxes,
                                                     u16* __restrict__ rbuf){
    __shared__ __align__(16) float planes[12544];   // [64][196] fp32, 50,176 B
    __shared__ int   offsL[54][16];
    __shared__ float wtsL[54][16];
    const int tid = threadIdx.x;
    if (blockIdx.x == 512){                          // zero row 1728
        for (int c = tid; c < 1024; c += 256) rbuf[(size_t)1728 * 1024 + c] = 0;
        return;
    }
    const int f  = blockIdx.x >> 4;
    const int c0 = (blockIdx.x & 15) << 6;

    // 1) coalesced load: 3136 float4 = one contiguous span
    const float4* src = (const float4*)(fmaps + ((size_t)f * 1024 + c0) * 196);
    float4* dl = (float4*)planes;
    for (int i = tid; i < 3136; i += 256) dl[i] = src[i];

    // 2) per-ROI bilinear taps (threads 0..53), 0.25 averaging factor folded into weights
    if (tid < 54){
        const int b = tid / 9, sp = tid % 9;
        const int oh = sp / 3, ow = sp % 3;
        const float* bx = boxes + (f * 6 + b) * 4;
        float x1 = bx[0], y1 = bx[1], x2 = bx[2], y2 = bx[3];
        float bw = fmaxf(x2 - x1, 1.0f) * (1.0f / 3.0f);
        float bh = fmaxf(y2 - y1, 1.0f) * (1.0f / 3.0f);
        int iy0[2], iy1[2], ix0[2], ix1[2];
        float ly[2], lx[2];
#pragma unroll
        for (int s = 0; s < 2; ++s){
            float gy = (float)oh + (s + 0.5f) * 0.5f;
            float ys = y1 + bh * gy;
            float y0f = floorf(ys); y0f = fminf(fmaxf(y0f, 0.f), 13.f);
            ly[s] = fminf(fmaxf(ys - y0f, 0.f), 1.f);
            iy0[s] = (int)y0f; iy1[s] = min(iy0[s] + 1, 13);
            float gx = (float)ow + (s + 0.5f) * 0.5f;
            float xs = x1 + bw * gx;
            float x0f = floorf(xs); x0f = fminf(fmaxf(x0f, 0.f), 13.f);
            lx[s] = fminf(fmaxf(xs - x0f, 0.f), 1.f);
            ix0[s] = (int)x0f; ix1[s] = min(ix0[s] + 1, 13);
        }
        int idx = 0;
#pragma unroll
        for (int sy = 0; sy < 2; ++sy)
#pragma unroll
            for (int sx = 0; sx < 2; ++sx){
                float wy1v = ly[sy], wy0v = 1.f - wy1v;
                float wx1v = lx[sx], wx0v = 1.f - wx1v;
                offsL[tid][idx] = iy0[sy] * 14 + ix0[sx]; wtsL[tid][idx] = wy0v * wx0v * 0.25f; idx++;
                offsL[tid][idx] = iy0[sy] * 14 + ix1[sx]; wtsL[tid][idx] = wy0v * wx1v * 0.25f; idx++;
                offsL[tid][idx] = iy1[sy] * 14 + ix0[sx]; wtsL[tid][idx] = wy1v * wx0v * 0.25f; idx++;
                offsL[tid][idx] = iy1[sy] * 14 + ix1[sx]; wtsL[tid][idx] = wy1v * wx1v * 0.25f; idx++;
            }
    }
    __syncthreads();

    // 3) sample: wave wv owns channels c0+wv*16..+16, lane l = ROI (54 active)
    const int wv = tid >> 6, l = tid & 63;
    if (l < 54){
        int offr[16]; float wtr[16];
#pragma unroll
        for (int i = 0; i < 16; ++i){ offr[i] = offsL[l][i]; wtr[i] = wtsL[l][i]; }
        unsigned pk[8];
#pragma unroll
        for (int jp = 0; jp < 8; ++jp){
            const float* p0 = planes + (wv * 16 + jp * 2) * 196;
            const float* p1 = p0 + 196;
            float a0 = 0.f, a1 = 0.f;
#pragma unroll
            for (int i = 0; i < 16; ++i){
                a0 += p0[offr[i]] * wtr[i];
                a1 += p1[offr[i]] * wtr[i];
            }
            pk[jp] = (unsigned)f2bf(a0) | ((unsigned)f2bf(a1) << 16);
        }
        u16* drow = rbuf + (size_t)(f * 54 + l) * 1024 + c0 + wv * 16;
        *(u32x4*)(drow)     = (u32x4){pk[0], pk[1], pk[2], pk[3]};
        *(u32x4*)(drow + 8) = (u32x4){pk[4], pk[5], pk[6], pk[7]};
    }
}

// ---------------- rowidx[fb][t] = rbuf row base (r*9) of matched person, or -1 ------------
__global__ void rowidx_kernel(const int* __restrict__ pid, int* __restrict__ rowidx){
    int i = blockIdx.x * blockDim.x + threadIdx.x;   // 960 = 192*5
    if (i >= 960) return;
    int fb = i / 5, t = i % 5;
    int f = fb / 6, b = fb % 6;
    int start = max(f - 2, 0);
    int end = min(start + 4, 31);
    int span = end - start;
    int g = start + (t * span) / 4;
    int p = pid[f * 6 + b];
    int r = -1;
#pragma unroll
    for (int j = 0; j < 6; ++j)
        if (pid[g * 6 + j] == p){ r = (g * 6 + j) * 9; break; }
    rowidx[i] = r;
}

// ---------------- stage A: per-tap GEMM  P[tap][mb][r][128] = rbuf[r] . Wt1[oc][tap] ------
// m97 structure: 128x128 tile, BK=64, global_load_lds w16, linear LDS [128][64] u16 with
// XOR bank-swizzle applied as pre-swizzled GLOBAL source + swizzled ds_read (rule #21).
__global__ __launch_bounds__(256, 4) void tapgemm_kernel(
        const u16* __restrict__ Wt1,     // [512][27][1024] bf16
        const u16* __restrict__ rb,      // [1729][1024] bf16 (row 1728 = 0)
        u16* __restrict__ P)             // [27][4][1728][128] bf16 (block-contiguous tiles)
{
    __shared__ u16 lds[16384];           // 32 KB: As [128][64] + Bs [128][64]
    u16* As = lds;
    u16* Bs = lds + 8192;
    const int tid = threadIdx.x;
    const int m0 = blockIdx.x * 128;     // oc
    const int n0 = blockIdx.y * 128;     // r
    const int tap = blockIdx.z;

    // ---- staging geometry: issue (w,j) covers rows w*32+j*8 .. +8 of the 128x64 tile ----
    const int w   = tid >> 6;            // wave
    const int l   = tid & 63;
    const int sub = l >> 3;              // row within 8-row group
    const int csw = (l & 7) ^ sub;       // logical K-chunk for this lane (pre-swizzled source)
    const int rowb = w * 32 + sub;
    const char* gA = (const char*)Wt1 + (size_t)(m0 + rowb) * 55296 + tap * 2048 + csw * 16;
    const char* gB[4];
#pragma unroll
    for (int j = 0; j < 4; ++j){
        int gr = min(n0 + rowb + j * 8, 1728);       // clamp to zero row
        gB[j] = (const char*)rb + (size_t)gr * 2048 + csw * 16;
    }

    const int lane = tid & 63, wv = tid >> 6;
    const int wm = (wv & 1) * 64, wn = (wv >> 1) * 64;
    const int lid = lane & 15, q = lane >> 4;
    const int xr = (lid & 7) << 4;       // read-side swizzle (row&7 == lid&7 for all frags)
    f32x4 acc[4][4];
#pragma unroll
    for (int i = 0; i < 4; ++i)
#pragma unroll
        for (int j = 0; j < 4; ++j) acc[i][j] = (f32x4){0.f, 0.f, 0.f, 0.f};

    for (int kt = 0; kt < 16; ++kt){
        __syncthreads();                 // prior tile fully consumed
#pragma unroll
        for (int j = 0; j < 4; ++j)
            GLOAD_LDS16(gA + (size_t)j * 442368 + kt * 128, &As[(w * 4 + j) * 512]);
#pragma unroll
        for (int j = 0; j < 4; ++j)
            GLOAD_LDS16(gB[j] + kt * 128, &Bs[(w * 4 + j) * 512]);
        __syncthreads();                 // vmcnt drain: staged data visible
#pragma unroll
        for (int ks = 0; ks < 2; ++ks){
            s16x8 af[4], bf[4];
            const int cb = ks * 64 + q * 16;
#pragma unroll
            for (int mi = 0; mi < 4; ++mi)
                af[mi] = *(const s16x8*)((const char*)As + (wm + mi * 16 + lid) * 128 + (cb ^ xr));
#pragma unroll
            for (int ni = 0; ni < 4; ++ni)
                bf[ni] = *(const s16x8*)((const char*)Bs + (wn + ni * 16 + lid) * 128 + (cb ^ xr));
#pragma unroll
            for (int mi = 0; mi < 4; ++mi)
#pragma unroll
                for (int ni = 0; ni < 4; ++ni)
                    acc[mi][ni] = __builtin_amdgcn_mfma_f32_16x16x32_bf16(af[mi], bf[ni], acc[mi][ni], 0, 0, 0);
        }
    }

    // ---- epilogue: LDS-transpose (swizzled, [128 r][256 B]) + contiguous NT writeout ----
    __syncthreads();
#pragma unroll
    for (int mi = 0; mi < 4; ++mi){
        const int colb = (wm + mi * 16 + q * 4) * 2;   // oc-local byte col
#pragma unroll
        for (int ni = 0; ni < 4; ++ni){
            const int row = wn + ni * 16 + lid;        // r-local
            ushort4 o;
            o.x = f2bf(acc[mi][ni][0]);
            o.y = f2bf(acc[mi][ni][1]);
            o.z = f2bf(acc[mi][ni][2]);
            o.w = f2bf(acc[mi][ni][3]);
            *(ushort4*)((char*)lds + row * 256 + (colb ^ xr)) = o;
        }
    }
    __syncthreads();
    // block tile = ONE contiguous 32 KB span of P; stream it out with NT full-line stores
    u16* Pt = P + (((size_t)tap * 4 + blockIdx.x) * 1728 + n0) * 128;
    const int trow = tid >> 4;          // 0..15
    const int c    = tid & 15;          // 16 B chunk within the 256 B row
#pragma unroll
    for (int it = 0; it < 8; ++it){
        const int rl = it * 16 + trow;
        if (n0 + rl < 1728){
            const int pc = (c & 8) | ((c & 7) ^ (rl & 7));
            u32x4 v = *(const u32x4*)((const char*)lds + rl * 256 + pc * 16);
            __builtin_nontemporal_store(v, (u32x4*)(Pt + (size_t)rl * 128 + c * 8));
        }
    }
}

// ---------------- stage B: y[n][oc] = relu(b1 + sum_tap P[tap][mb][src][128]) -------------
__global__ __launch_bounds__(256) void reduce_kernel(
        const unsigned* __restrict__ P32,   // [27][4][1728][64] (u32 = 2 bf16)
        const int* __restrict__ rowidx,     // [192][5]
        const float* __restrict__ b1,       // [512]
        unsigned* __restrict__ y32)         // [8640][256]
{
    __shared__ int rows[27];
    const int n = blockIdx.x;             // 0..8639
    const int tid = threadIdx.x;
    const int fb = n / 45, rr = n % 45;
    const int od = rr / 9, oh = (rr % 9) / 3, ow = rr % 3;
    if (tid < 27){
        int kd = tid / 9, kh = (tid % 9) / 3, kw = tid % 3;
        int t = od + kd - 1, h = oh + kh - 1, w = ow + kw - 1;
        int row = -1;
        if ((unsigned)t < 5u && (unsigned)h < 3u && (unsigned)w < 3u){
            int rbv = rowidx[fb * 5 + t];
            if (rbv >= 0) row = rbv + h * 3 + w;
        }
        rows[tid] = row;
    }
    __syncthreads();
    const int mb = tid >> 6;              // oc-block of this thread's u32 pair
    const int lc = tid & 63;
    float a0 = 0.f, a1 = 0.f;
#pragma unroll
    for (int tap = 0; tap < 27; ++tap){
        int r = rows[tap];
        if (r >= 0){
            unsigned v = P32[(((size_t)tap * 4 + mb) * 1728 + r) * 64 + lc];
            a0 += bflo2f(v);
            a1 += bfhi2f(v);
        }
    }
    a0 = fmaxf(a0 + b1[tid * 2], 0.f);
    a1 = fmaxf(a1 + b1[tid * 2 + 1], 0.f);
    y32[(size_t)n * 256 + tid] = (unsigned)f2bf(a0) | ((unsigned)f2bf(a1) << 16);
}

// ---------------- GEMM2: conv1b, 64x64 tile, BK=64, split-K=27 (one tap per split) --------
// m97 structure (same as tapgemm, 64-row variant): global_load_lds w16 + swizzle pair.
// zpart is block-contiguous [27][4][576][64] f32, streamed with NT full-line stores.
__global__ __launch_bounds__(256, 4) void gemm2_kernel(
        const u16* __restrict__ Wt2,   // [256][13824] bf16, k = tap*512+ic
        const u16* __restrict__ y,     // [8640][512] bf16; row n=fb*45+od*9+sp
        float* __restrict__ zpart)     // [27][4][576][64] f32
{
    __shared__ u16 lds[8192];          // 16 KB: As [64][64] + Bs [64][64] u16
    u16* As = lds;
    u16* Bs = lds + 4096;
    const int tid = threadIdx.x;
    const int m0 = blockIdx.x * 64;    // oc2
    const int n0 = blockIdx.y * 64;    // n (fb*3+od)
    const int kz = blockIdx.z;         // tap 0..26

    // staging geometry: wave w, issue j covers rows w*16+j*8..+8 of the 64x64 tile
    const int w   = tid >> 6;
    const int l   = tid & 63;
    const int sub = l >> 3;
    const int csw = (l & 7) ^ sub;     // pre-swizzled source K-chunk
    const int rowb = w * 16 + sub;
    const char* gA = (const char*)Wt2 + (size_t)(m0 + rowb) * 27648 + kz * 1024 + csw * 16;
    const char* gB[2];
#pragma unroll
    for (int j = 0; j < 2; ++j){
        const int n2 = n0 + rowb + j * 8;
        const int fb = n2 / 3, od2 = n2 - fb * 3;
        gB[j] = (const char*)y + ((size_t)(fb * 45 + od2 * 9) + kz) * 1024 + csw * 16;
    }

    const int lane = tid & 63, wv = tid >> 6;
    const int wm = (wv & 1) * 32, wn = (wv >> 1) * 32;
    const int lid = lane & 15, q = lane >> 4;
    const int xr = (lid & 7) << 4;
    f32x4 acc[2][2];
#pragma unroll
    for (int i = 0; i < 2; ++i)
#pragma unroll
        for (int j = 0; j < 2; ++j) acc[i][j] = (f32x4){0.f, 0.f, 0.f, 0.f};

    for (int kt = 0; kt < 8; ++kt){
        __syncthreads();
#pragma unroll
        for (int j = 0; j < 2; ++j)
            GLOAD_LDS16(gA + (size_t)j * 221184 + kt * 128, &As[(w * 2 + j) * 512]);
#pragma unroll
        for (int j = 0; j < 2; ++j)
            GLOAD_LDS16(gB[j] + kt * 128, &Bs[(w * 2 + j) * 512]);
        __syncthreads();
#pragma unroll
        for (int ks = 0; ks < 2; ++ks){
            s16x8 af[2], bf[2];
            const int cb = ks * 64 + q * 16;
#pragma unroll
            for (int mi = 0; mi < 2; ++mi)
                af[mi] = *(const s16x8*)((const char*)As + (wm + mi * 16 + lid) * 128 + (cb ^ xr));
#pragma unroll
            for (int ni = 0; ni < 2; ++ni)
                bf[ni] = *(const s16x8*)((const char*)Bs + (wn + ni * 16 + lid) * 128 + (cb ^ xr));
#pragma unroll
            for (int mi = 0; mi < 2; ++mi)
#pragma unroll
                for (int ni = 0; ni < 2; ++ni)
                    acc[mi][ni] = __builtin_amdgcn_mfma_f32_16x16x32_bf16(af[mi], bf[ni], acc[mi][ni], 0, 0, 0);
        }
    }

    // ---- epilogue: stage f32 tile [64 n][64 oc] in LDS (swizzled) + contiguous NT out ----
    __syncthreads();
#pragma unroll
    for (int mi = 0; mi < 2; ++mi){
        const int colb = (wm + mi * 16 + q * 4) * 4;   // oc-local byte col (f32)
#pragma unroll
        for (int ni = 0; ni < 2; ++ni){
            const int row = wn + ni * 16 + lid;        // n-local
            *(f32x4*)((char*)lds + row * 256 + (colb ^ xr)) = acc[mi][ni];
        }
    }
    __syncthreads();
    float* zb = zpart + (((size_t)kz * 4 + blockIdx.x) * 576 + n0) * 64;
    const int trow = tid >> 4;          // 0..15
    const int c    = tid & 15;          // 16 B chunk within the 256 B row
#pragma unroll
    for (int it = 0; it < 4; ++it){
        const int rl = it * 16 + trow;
        const int pc = (c & 8) | ((c & 7) ^ (rl & 7));
        u32x4 v = *(const u32x4*)((const char*)lds + rl * 256 + pc * 16);
        __builtin_nontemporal_store(v, (u32x4*)(zb + (size_t)rl * 64 + c * 4));
    }
}

// ---------------- final: sum split-K + bias + relu + max over D + FC 256->27 (fp32 out) ----
__global__ __launch_bounds__(256) void final_kernel(
        const float* __restrict__ zpart,   // [27][4][576][64]
        const float* __restrict__ b2,
        const float* __restrict__ fcw, const float* __restrict__ fcb,
        float* __restrict__ out){
    __shared__ float smv[256];
    const int fb = blockIdx.x, tid = threadIdx.x;
    const int mb = tid >> 6, c = tid & 63;       // oc = mb*64 + c = tid
    const float bias = b2[tid];
    float mv = 0.f;
#pragma unroll
    for (int od = 0; od < 3; ++od){
        const int n = fb * 3 + od;
        float s = 0.f;
#pragma unroll
        for (int kz = 0; kz < 27; ++kz)
            s += zpart[(((size_t)kz * 4 + mb) * 576 + n) * 64 + c];
        s = fmaxf(s + bias, 0.f);
        mv = fmaxf(mv, s);
    }
    smv[tid] = mv;
    __syncthreads();
    const int wv = tid >> 6, lane = tid & 63;
    for (int cls = wv; cls < 27; cls += 4){
        const float* wrow = fcw + cls * 256;
        float s = 0.f;
#pragma unroll
        for (int j = 0; j < 4; ++j) s += smv[lane + j * 64] * wrow[lane + j * 64];
#pragma unroll
        for (int off = 32; off > 0; off >>= 1) s += __shfl_xor(s, off);
        if (lane == 0) out[fb * 27 + cls] = s + fcb[cls];
    }
}

extern "C" void kernel_launch(void* const* d_in, const int* in_sizes, int n_in,
                              void* d_out, int out_size, void* d_ws, size_t ws_size,
                              hipStream_t stream){
    const float* fmaps = (const float*)d_in[0];
    const float* boxes = (const float*)d_in[1];
    const int*   pid   = (const int*)d_in[2];
    const float* w1    = (const float*)d_in[3];
    const float* b1    = (const float*)d_in[4];
    const float* w2    = (const float*)d_in[5];
    const float* b2    = (const float*)d_in[6];
    const float* fcw   = (const float*)d_in[7];
    const float* fcb   = (const float*)d_in[8];
    float* out = (float*)d_out;

    // ---- workspace layout: TOTAL 86,710,528 B (86.7 MB) ----
    // [rbuf 3,541,248][rowidx 4,096][Wt1 28,311,552 | alias: y 8,847,360 + zpart 15,925,248]
    // [Wt2 7,077,888][P 47,775,744]
    char* ws = (char*)d_ws;
    u16*   rbuf  = (u16*)(ws);
    int*   rowidx= (int*)(ws + 3541248);
    u16*   Wt1   = (u16*)(ws + 3545344);
    u16*   y     = (u16*)(ws + 3545344);                    // aliases Wt1 (dead after tapgemm)
    float* zpart = (float*)(ws + 3545344 + 8847360);        // also inside Wt1 region (24.8 MB used of 28.3)
    u16*   Wt2   = (u16*)(ws + 3545344 + 28311552);
    u16*   P     = (u16*)(ws + 3545344 + 28311552 + 7077888);

    // w1: C=1024 (CShift=10), Cb=512 (cbShift=9) -> 1024 blocks, 27,648 B LDS
    hipLaunchKernelGGL(prep_w_kernel, dim3(1024), dim3(256), 512 * 27 * 2, stream, w1, Wt1, 9, 10);
    // w2: C=512 (CShift=9), Cb=256 (cbShift=8) -> 512 blocks, 13,824 B LDS
    hipLaunchKernelGGL(prep_w_kernel, dim3(512), dim3(256), 256 * 27 * 2, stream, w2, Wt2, 8, 9);
    hipLaunchKernelGGL(roi_kernel, dim3(513), dim3(256), 0, stream, fmaps, boxes, rbuf);
    hipLaunchKernelGGL(rowidx_kernel, dim3(4), dim3(256), 0, stream, pid, rowidx);
    hipLaunchKernelGGL(tapgemm_kernel, dim3(4, 14, 27), dim3(256), 0, stream, Wt1, rbuf, P);
    hipLaunchKernelGGL(reduce_kernel, dim3(8640), dim3(256), 0, stream,
                       (const unsigned*)P, rowidx, b1, (unsigned*)y);
    hipLaunchKernelGGL(gemm2_kernel, dim3(4, 9, 27), dim3(256), 0, stream, Wt2, y, zpart);
    hipLaunchKernelGGL(final_kernel, dim3(192), dim3(256), 0, stream, zpart, b2, fcw, fcb, out);
}

// Round 8
// 277.368 us; speedup vs baseline: 2.8477x; 1.0204x over previous
//
#include <hip/hip_runtime.h>

typedef short s16x8 __attribute__((ext_vector_type(8)));   // 8 bf16 raw bits
typedef float f32x4 __attribute__((ext_vector_type(4)));
typedef unsigned u32x4 __attribute__((ext_vector_type(4)));
typedef unsigned short u16;

__device__ __forceinline__ u16 f2bf(float x){
    unsigned u = __float_as_uint(x);
    unsigned r = u + 0x7fffu + ((u >> 16) & 1u);
    return (u16)(r >> 16);
}
__device__ __forceinline__ float bfhi2f(unsigned v){ return __uint_as_float(v & 0xFFFF0000u); }
__device__ __forceinline__ float bflo2f(unsigned v){ return __uint_as_float(v << 16); }

// async global->LDS, 16B per lane; LDS dest is wave-uniform base + lane*16 (HW), src is per-lane
#define GLOAD_LDS16(g, l) __builtin_amdgcn_global_load_lds( \
        (const __attribute__((address_space(1))) void*)(g), \
        (__attribute__((address_space(3))) void*)(l), 16, 0, 0)

// ================= fused front-end: roi | prep(w1) | prep(w2) | rowidx ====================
// These four stages are mutually independent; fusing them into one grid overlaps roi's
// latency-bound phase with prep's BW-bound phase instead of serializing 4 launches.

__device__ __forceinline__ void prep_body(char* smem, const float* __restrict__ in,
                                          u16* __restrict__ out, int pb,
                                          int cbShift, int CShift){
    u16* lds = (u16*)smem;                             // [Cb][27] u16, linear
    const int Cb = 1 << cbShift;
    const int C  = 1 << CShift;
    const int splitShift = CShift - cbShift;           // = 1
    const int oc  = pb >> splitShift;
    const int ic0 = (pb & ((1 << splitShift) - 1)) << cbShift;
    const int n4 = (27 << cbShift) >> 2;               // float4 count
    const int tid = threadIdx.x;

    const float4* src = (const float4*)(in + ((size_t)oc * C + ic0) * 27);
#pragma unroll 4
    for (int i = tid; i < n4; i += 256){
        float4 v = src[i];
        ushort4 o;
        o.x = f2bf(v.x); o.y = f2bf(v.y); o.z = f2bf(v.z); o.w = f2bf(v.w);
        *(ushort4*)&lds[i * 4] = o;
    }
    __syncthreads();
    u16* dst = out + (size_t)oc * 27 * C + ic0;
#pragma unroll 4
    for (int j = tid; j < n4; j += 256){
        const int jj  = j << 2;
        const int tap = jj >> cbShift;
        const int icl = jj & (Cb - 1);
        ushort4 o;
        o.x = lds[(icl    ) * 27 + tap];
        o.y = lds[(icl + 1) * 27 + tap];
        o.z = lds[(icl + 2) * 27 + tap];
        o.w = lds[(icl + 3) * 27 + tap];
        *(ushort4*)(dst + (size_t)tap * C + icl) = o;
    }
}

__device__ __forceinline__ void roi_body(char* smem, const float* __restrict__ fmaps,
                                         const float* __restrict__ boxes,
                                         u16* __restrict__ rbuf, int blk){
    float* planes = (float*)smem;                      // [64][196] fp32, 50,176 B
    int   (*offsL)[16] = (int(*)[16])(smem + 50176);   // 3,456 B
    float (*wtsL)[16]  = (float(*)[16])(smem + 50176 + 3456);
    const int tid = threadIdx.x;
    if (blk == 512){                                   // zero row 1728
        for (int c = tid; c < 1024; c += 256) rbuf[(size_t)1728 * 1024 + c] = 0;
        return;
    }
    const int f  = blk >> 4;
    const int c0 = (blk & 15) << 6;

    // 1) coalesced load: 3136 float4 = one contiguous span
    const float4* src = (const float4*)(fmaps + ((size_t)f * 1024 + c0) * 196);
    float4* dl = (float4*)planes;
    for (int i = tid; i < 3136; i += 256) dl[i] = src[i];

    // 2) per-ROI bilinear taps (threads 0..53), 0.25 averaging factor folded into weights
    if (tid < 54){
        const int b = tid / 9, sp = tid % 9;
        const int oh = sp / 3, ow = sp % 3;
        const float* bx = boxes + (f * 6 + b) * 4;
        float x1 = bx[0], y1 = bx[1], x2 = bx[2], y2 = bx[3];
        float bw = fmaxf(x2 - x1, 1.0f) * (1.0f / 3.0f);
        float bh = fmaxf(y2 - y1, 1.0f) * (1.0f / 3.0f);
        int iy0[2], iy1[2], ix0[2], ix1[2];
        float ly[2], lx[2];
#pragma unroll
        for (int s = 0; s < 2; ++s){
            float gy = (float)oh + (s + 0.5f) * 0.5f;
            float ys = y1 + bh * gy;
            float y0f = floorf(ys); y0f = fminf(fmaxf(y0f, 0.f), 13.f);
            ly[s] = fminf(fmaxf(ys - y0f, 0.f), 1.f);
            iy0[s] = (int)y0f; iy1[s] = min(iy0[s] + 1, 13);
            float gx = (float)ow + (s + 0.5f) * 0.5f;
            float xs = x1 + bw * gx;
            float x0f = floorf(xs); x0f = fminf(fmaxf(x0f, 0.f), 13.f);
            lx[s] = fminf(fmaxf(xs - x0f, 0.f), 1.f);
            ix0[s] = (int)x0f; ix1[s] = min(ix0[s] + 1, 13);
        }
        int idx = 0;
#pragma unroll
        for (int sy = 0; sy < 2; ++sy)
#pragma unroll
            for (int sx = 0; sx < 2; ++sx){
                float wy1v = ly[sy], wy0v = 1.f - wy1v;
                float wx1v = lx[sx], wx0v = 1.f - wx1v;
                offsL[tid][idx] = iy0[sy] * 14 + ix0[sx]; wtsL[tid][idx] = wy0v * wx0v * 0.25f; idx++;
                offsL[tid][idx] = iy0[sy] * 14 + ix1[sx]; wtsL[tid][idx] = wy0v * wx1v * 0.25f; idx++;
                offsL[tid][idx] = iy1[sy] * 14 + ix0[sx]; wtsL[tid][idx] = wy1v * wx0v * 0.25f; idx++;
                offsL[tid][idx] = iy1[sy] * 14 + ix1[sx]; wtsL[tid][idx] = wy1v * wx1v * 0.25f; idx++;
            }
    }
    __syncthreads();

    // 3) sample: wave wv owns channels c0+wv*16..+16, lane l = ROI (54 active)
    const int wv = tid >> 6, l = tid & 63;
    if (l < 54){
        int offr[16]; float wtr[16];
#pragma unroll
        for (int i = 0; i < 16; ++i){ offr[i] = offsL[l][i]; wtr[i] = wtsL[l][i]; }
        unsigned pk[8];
#pragma unroll
        for (int jp = 0; jp < 8; ++jp){
            const float* p0 = planes + (wv * 16 + jp * 2) * 196;
            const float* p1 = p0 + 196;
            float a0 = 0.f, a1 = 0.f;
#pragma unroll
            for (int i = 0; i < 16; ++i){
                a0 += p0[offr[i]] * wtr[i];
                a1 += p1[offr[i]] * wtr[i];
            }
            pk[jp] = (unsigned)f2bf(a0) | ((unsigned)f2bf(a1) << 16);
        }
        u16* drow = rbuf + (size_t)(f * 54 + l) * 1024 + c0 + wv * 16;
        *(u32x4*)(drow)     = (u32x4){pk[0], pk[1], pk[2], pk[3]};
        *(u32x4*)(drow + 8) = (u32x4){pk[4], pk[5], pk[6], pk[7]};
    }
}

__device__ __forceinline__ void rowidx_body(const int* __restrict__ pid,
                                            int* __restrict__ rowidx, int blk){
    int i = blk * 256 + threadIdx.x;                   // 960 = 192*5
    if (i >= 960) return;
    int fb = i / 5, t = i % 5;
    int f = fb / 6, b = fb % 6;
    int start = max(f - 2, 0);
    int end = min(start + 4, 31);
    int span = end - start;
    int g = start + (t * span) / 4;
    int p = pid[f * 6 + b];
    int r = -1;
#pragma unroll
    for (int j = 0; j < 6; ++j)
        if (pid[g * 6 + j] == p){ r = (g * 6 + j) * 9; break; }
    rowidx[i] = r;
}

__global__ __launch_bounds__(256) void front_kernel(
        const float* __restrict__ fmaps, const float* __restrict__ boxes,
        const int* __restrict__ pid,
        const float* __restrict__ w1, const float* __restrict__ w2,
        u16* __restrict__ rbuf, u16* __restrict__ Wt1, u16* __restrict__ Wt2,
        int* __restrict__ rowidx){
    extern __shared__ __align__(16) char smem[];       // 57,088 B dynamic
    const int bid = blockIdx.x;
    if (bid < 513)       roi_body(smem, fmaps, boxes, rbuf, bid);
    else if (bid < 1537) prep_body(smem, w1, Wt1, bid - 513, 9, 10);
    else if (bid < 2049) prep_body(smem, w2, Wt2, bid - 1537, 8, 9);
    else                 rowidx_body(pid, rowidx, bid - 2049);
}

// ---------------- stage A: per-tap GEMM  P[tap][mb][r][128] = rbuf[r] . Wt1[oc][tap] ------
// m97 structure: 128x128 tile, BK=64, global_load_lds w16, linear LDS [128][64] u16 with
// XOR bank-swizzle applied as pre-swizzled GLOBAL source + swizzled ds_read (rule #21).
__global__ __launch_bounds__(256, 4) void tapgemm_kernel(
        const u16* __restrict__ Wt1,     // [512][27][1024] bf16
        const u16* __restrict__ rb,      // [1729][1024] bf16 (row 1728 = 0)
        u16* __restrict__ P)             // [27][4][1728][128] bf16 (block-contiguous tiles)
{
    __shared__ u16 lds[16384];           // 32 KB: As [128][64] + Bs [128][64]
    u16* As = lds;
    u16* Bs = lds + 8192;
    const int tid = threadIdx.x;
    const int m0 = blockIdx.x * 128;     // oc
    const int n0 = blockIdx.y * 128;     // r
    const int tap = blockIdx.z;

    // ---- staging geometry: issue (w,j) covers rows w*32+j*8 .. +8 of the 128x64 tile ----
    const int w   = tid >> 6;            // wave
    const int l   = tid & 63;
    const int sub = l >> 3;              // row within 8-row group
    const int csw = (l & 7) ^ sub;       // logical K-chunk for this lane (pre-swizzled source)
    const int rowb = w * 32 + sub;
    const char* gA = (const char*)Wt1 + (size_t)(m0 + rowb) * 55296 + tap * 2048 + csw * 16;
    const char* gB[4];
#pragma unroll
    for (int j = 0; j < 4; ++j){
        int gr = min(n0 + rowb + j * 8, 1728);       // clamp to zero row
        gB[j] = (const char*)rb + (size_t)gr * 2048 + csw * 16;
    }

    const int lane = tid & 63, wv = tid >> 6;
    const int wm = (wv & 1) * 64, wn = (wv >> 1) * 64;
    const int lid = lane & 15, q = lane >> 4;
    const int xr = (lid & 7) << 4;       // read-side swizzle (row&7 == lid&7 for all frags)
    f32x4 acc[4][4];
#pragma unroll
    for (int i = 0; i < 4; ++i)
#pragma unroll
        for (int j = 0; j < 4; ++j) acc[i][j] = (f32x4){0.f, 0.f, 0.f, 0.f};

    for (int kt = 0; kt < 16; ++kt){
        __syncthreads();                 // prior tile fully consumed
#pragma unroll
        for (int j = 0; j < 4; ++j)
            GLOAD_LDS16(gA + (size_t)j * 442368 + kt * 128, &As[(w * 4 + j) * 512]);
#pragma unroll
        for (int j = 0; j < 4; ++j)
            GLOAD_LDS16(gB[j] + kt * 128, &Bs[(w * 4 + j) * 512]);
        __syncthreads();                 // vmcnt drain: staged data visible
#pragma unroll
        for (int ks = 0; ks < 2; ++ks){
            s16x8 af[4], bf[4];
            const int cb = ks * 64 + q * 16;
#pragma unroll
            for (int mi = 0; mi < 4; ++mi)
                af[mi] = *(const s16x8*)((const char*)As + (wm + mi * 16 + lid) * 128 + (cb ^ xr));
#pragma unroll
            for (int ni = 0; ni < 4; ++ni)
                bf[ni] = *(const s16x8*)((const char*)Bs + (wn + ni * 16 + lid) * 128 + (cb ^ xr));
#pragma unroll
            for (int mi = 0; mi < 4; ++mi)
#pragma unroll
                for (int ni = 0; ni < 4; ++ni)
                    acc[mi][ni] = __builtin_amdgcn_mfma_f32_16x16x32_bf16(af[mi], bf[ni], acc[mi][ni], 0, 0, 0);
        }
    }

    // ---- epilogue: LDS-transpose (swizzled, [128 r][256 B]) + contiguous NT writeout ----
    __syncthreads();
#pragma unroll
    for (int mi = 0; mi < 4; ++mi){
        const int colb = (wm + mi * 16 + q * 4) * 2;   // oc-local byte col
#pragma unroll
        for (int ni = 0; ni < 4; ++ni){
            const int row = wn + ni * 16 + lid;        // r-local
            ushort4 o;
            o.x = f2bf(acc[mi][ni][0]);
            o.y = f2bf(acc[mi][ni][1]);
            o.z = f2bf(acc[mi][ni][2]);
            o.w = f2bf(acc[mi][ni][3]);
            *(ushort4*)((char*)lds + row * 256 + (colb ^ xr)) = o;
        }
    }
    __syncthreads();
    // block tile = ONE contiguous 32 KB span of P; stream it out with NT full-line stores
    u16* Pt = P + (((size_t)tap * 4 + blockIdx.x) * 1728 + n0) * 128;
    const int trow = tid >> 4;          // 0..15
    const int c    = tid & 15;          // 16 B chunk within the 256 B row
#pragma unroll
    for (int it = 0; it < 8; ++it){
        const int rl = it * 16 + trow;
        if (n0 + rl < 1728){
            const int pc = (c & 8) | ((c & 7) ^ (rl & 7));
            u32x4 v = *(const u32x4*)((const char*)lds + rl * 256 + pc * 16);
            __builtin_nontemporal_store(v, (u32x4*)(Pt + (size_t)rl * 128 + c * 8));
        }
    }
}

// ---------------- stage B: y[n][oc] = relu(b1 + sum_tap P[tap][mb][src][128]) -------------
__global__ __launch_bounds__(256) void reduce_kernel(
        const unsigned* __restrict__ P32,   // [27][4][1728][64] (u32 = 2 bf16)
        const int* __restrict__ rowidx,     // [192][5]
        const float* __restrict__ b1,       // [512]
        unsigned* __restrict__ y32)         // [8640][256]
{
    __shared__ int rows[27];
    const int n = blockIdx.x;             // 0..8639
    const int tid = threadIdx.x;
    const int fb = n / 45, rr = n % 45;
    const int od = rr / 9, oh = (rr % 9) / 3, ow = rr % 3;
    if (tid < 27){
        int kd = tid / 9, kh = (tid % 9) / 3, kw = tid % 3;
        int t = od + kd - 1, h = oh + kh - 1, w = ow + kw - 1;
        int row = -1;
        if ((unsigned)t < 5u && (unsigned)h < 3u && (unsigned)w < 3u){
            int rbv = rowidx[fb * 5 + t];
            if (rbv >= 0) row = rbv + h * 3 + w;
        }
        rows[tid] = row;
    }
    __syncthreads();
    const int mb = tid >> 6;              // oc-block of this thread's u32 pair
    const int lc = tid & 63;
    float a0 = 0.f, a1 = 0.f;
#pragma unroll
    for (int tap = 0; tap < 27; ++tap){
        int r = rows[tap];
        if (r >= 0){
            unsigned v = P32[(((size_t)tap * 4 + mb) * 1728 + r) * 64 + lc];
            a0 += bflo2f(v);
            a1 += bfhi2f(v);
        }
    }
    a0 = fmaxf(a0 + b1[tid * 2], 0.f);
    a1 = fmaxf(a1 + b1[tid * 2 + 1], 0.f);
    y32[(size_t)n * 256 + tid] = (unsigned)f2bf(a0) | ((unsigned)f2bf(a1) << 16);
}

// ---------------- GEMM2: conv1b, 64x64 tile, BK=64, split-K=27 (one tap per split) --------
// m97 structure (same as tapgemm, 64-row variant): global_load_lds w16 + swizzle pair.
// zpart is block-contiguous [27][4][576][64] f32, streamed with NT full-line stores.
__global__ __launch_bounds__(256, 4) void gemm2_kernel(
        const u16* __restrict__ Wt2,   // [256][13824] bf16, k = tap*512+ic
        const u16* __restrict__ y,     // [8640][512] bf16; row n=fb*45+od*9+sp
        float* __restrict__ zpart)     // [27][4][576][64] f32
{
    __shared__ u16 lds[8192];          // 16 KB: As [64][64] + Bs [64][64] u16
    u16* As = lds;
    u16* Bs = lds + 4096;
    const int tid = threadIdx.x;
    const int m0 = blockIdx.x * 64;    // oc2
    const int n0 = blockIdx.y * 64;    // n (fb*3+od)
    const int kz = blockIdx.z;         // tap 0..26

    // staging geometry: wave w, issue j covers rows w*16+j*8..+8 of the 64x64 tile
    const int w   = tid >> 6;
    const int l   = tid & 63;
    const int sub = l >> 3;
    const int csw = (l & 7) ^ sub;     // pre-swizzled source K-chunk
    const int rowb = w * 16 + sub;
    const char* gA = (const char*)Wt2 + (size_t)(m0 + rowb) * 27648 + kz * 1024 + csw * 16;
    const char* gB[2];
#pragma unroll
    for (int j = 0; j < 2; ++j){
        const int n2 = n0 + rowb + j * 8;
        const int fb = n2 / 3, od2 = n2 - fb * 3;
        gB[j] = (const char*)y + ((size_t)(fb * 45 + od2 * 9) + kz) * 1024 + csw * 16;
    }

    const int lane = tid & 63, wv = tid >> 6;
    const int wm = (wv & 1) * 32, wn = (wv >> 1) * 32;
    const int lid = lane & 15, q = lane >> 4;
    const int xr = (lid & 7) << 4;
    f32x4 acc[2][2];
#pragma unroll
    for (int i = 0; i < 2; ++i)
#pragma unroll
        for (int j = 0; j < 2; ++j) acc[i][j] = (f32x4){0.f, 0.f, 0.f, 0.f};

    for (int kt = 0; kt < 8; ++kt){
        __syncthreads();
#pragma unroll
        for (int j = 0; j < 2; ++j)
            GLOAD_LDS16(gA + (size_t)j * 221184 + kt * 128, &As[(w * 2 + j) * 512]);
#pragma unroll
        for (int j = 0; j < 2; ++j)
            GLOAD_LDS16(gB[j] + kt * 128, &Bs[(w * 2 + j) * 512]);
        __syncthreads();
#pragma unroll
        for (int ks = 0; ks < 2; ++ks){
            s16x8 af[2], bf[2];
            const int cb = ks * 64 + q * 16;
#pragma unroll
            for (int mi = 0; mi < 2; ++mi)
                af[mi] = *(const s16x8*)((const char*)As + (wm + mi * 16 + lid) * 128 + (cb ^ xr));
#pragma unroll
            for (int ni = 0; ni < 2; ++ni)
                bf[ni] = *(const s16x8*)((const char*)Bs + (wn + ni * 16 + lid) * 128 + (cb ^ xr));
#pragma unroll
            for (int mi = 0; mi < 2; ++mi)
#pragma unroll
                for (int ni = 0; ni < 2; ++ni)
                    acc[mi][ni] = __builtin_amdgcn_mfma_f32_16x16x32_bf16(af[mi], bf[ni], acc[mi][ni], 0, 0, 0);
        }
    }

    // ---- epilogue: stage f32 tile [64 n][64 oc] in LDS (swizzled) + contiguous NT out ----
    __syncthreads();
#pragma unroll
    for (int mi = 0; mi < 2; ++mi){
        const int colb = (wm + mi * 16 + q * 4) * 4;   // oc-local byte col (f32)
#pragma unroll
        for (int ni = 0; ni < 2; ++ni){
            const int row = wn + ni * 16 + lid;        // n-local
            *(f32x4*)((char*)lds + row * 256 + (colb ^ xr)) = acc[mi][ni];
        }
    }
    __syncthreads();
    float* zb = zpart + (((size_t)kz * 4 + blockIdx.x) * 576 + n0) * 64;
    const int trow = tid >> 4;          // 0..15
    const int c    = tid & 15;          // 16 B chunk within the 256 B row
#pragma unroll
    for (int it = 0; it < 4; ++it){
        const int rl = it * 16 + trow;
        const int pc = (c & 8) | ((c & 7) ^ (rl & 7));
        u32x4 v = *(const u32x4*)((const char*)lds + rl * 256 + pc * 16);
        __builtin_nontemporal_store(v, (u32x4*)(zb + (size_t)rl * 64 + c * 4));
    }
}

// ---------------- final: sum split-K + bias + relu + max over D + FC 256->27 (fp32 out) ----
__global__ __launch_bounds__(256) void final_kernel(
        const float* __restrict__ zpart,   // [27][4][576][64]
        const float* __restrict__ b2,
        const float* __restrict__ fcw, const float* __restrict__ fcb,
        float* __restrict__ out){
    __shared__ float smv[256];
    const int fb = blockIdx.x, tid = threadIdx.x;
    const int mb = tid >> 6, c = tid & 63;       // oc = mb*64 + c = tid
    const float bias = b2[tid];
    float mv = 0.f;
#pragma unroll
    for (int od = 0; od < 3; ++od){
        const int n = fb * 3 + od;
        float s = 0.f;
#pragma unroll
        for (int kz = 0; kz < 27; ++kz)
            s += zpart[(((size_t)kz * 4 + mb) * 576 + n) * 64 + c];
        s = fmaxf(s + bias, 0.f);
        mv = fmaxf(mv, s);
    }
    smv[tid] = mv;
    __syncthreads();
    const int wv = tid >> 6, lane = tid & 63;
    for (int cls = wv; cls < 27; cls += 4){
        const float* wrow = fcw + cls * 256;
        float s = 0.f;
#pragma unroll
        for (int j = 0; j < 4; ++j) s += smv[lane + j * 64] * wrow[lane + j * 64];
#pragma unroll
        for (int off = 32; off > 0; off >>= 1) s += __shfl_xor(s, off);
        if (lane == 0) out[fb * 27 + cls] = s + fcb[cls];
    }
}

extern "C" void kernel_launch(void* const* d_in, const int* in_sizes, int n_in,
                              void* d_out, int out_size, void* d_ws, size_t ws_size,
                              hipStream_t stream){
    const float* fmaps = (const float*)d_in[0];
    const float* boxes = (const float*)d_in[1];
    const int*   pid   = (const int*)d_in[2];
    const float* w1    = (const float*)d_in[3];
    const float* b1    = (const float*)d_in[4];
    const float* w2    = (const float*)d_in[5];
    const float* b2    = (const float*)d_in[6];
    const float* fcw   = (const float*)d_in[7];
    const float* fcb   = (const float*)d_in[8];
    float* out = (float*)d_out;

    // ---- workspace layout: TOTAL 86,710,528 B (86.7 MB) ----
    // [rbuf 3,541,248][rowidx 4,096][Wt1 28,311,552 | alias: y 8,847,360 + zpart 15,925,248]
    // [Wt2 7,077,888][P 47,775,744]
    char* ws = (char*)d_ws;
    u16*   rbuf  = (u16*)(ws);
    int*   rowidx= (int*)(ws + 3541248);
    u16*   Wt1   = (u16*)(ws + 3545344);
    u16*   y     = (u16*)(ws + 3545344);                    // aliases Wt1 (dead after tapgemm)
    float* zpart = (float*)(ws + 3545344 + 8847360);        // also inside Wt1 region (24.8 MB used of 28.3)
    u16*   Wt2   = (u16*)(ws + 3545344 + 28311552);
    u16*   P     = (u16*)(ws + 3545344 + 28311552 + 7077888);

    // fused front-end: roi (513) | prep w1 (1024) | prep w2 (512) | rowidx (4)
    hipLaunchKernelGGL(front_kernel, dim3(2053), dim3(256), 57088, stream,
                       fmaps, boxes, pid, w1, w2, rbuf, Wt1, Wt2, rowidx);
    hipLaunchKernelGGL(tapgemm_kernel, dim3(4, 14, 27), dim3(256), 0, stream, Wt1, rbuf, P);
    hipLaunchKernelGGL(reduce_kernel, dim3(8640), dim3(256), 0, stream,
                       (const unsigned*)P, rowidx, b1, (unsigned*)y);
    hipLaunchKernelGGL(gemm2_kernel, dim3(4, 9, 27), dim3(256), 0, stream, Wt2, y, zpart);
    hipLaunchKernelGGL(final_kernel, dim3(192), dim3(256), 0, stream, zpart, b2, fcw, fcb, out);
}

// Round 9
// 243.673 us; speedup vs baseline: 3.2415x; 1.1383x over previous
//
#include <hip/hip_runtime.h>

typedef short s16x8 __attribute__((ext_vector_type(8)));   // 8 bf16 raw bits
typedef float f32x4 __attribute__((ext_vector_type(4)));
typedef unsigned u32x4 __attribute__((ext_vector_type(4)));
typedef unsigned short u16;

__device__ __forceinline__ u16 f2bf(float x){
    unsigned u = __float_as_uint(x);
    unsigned r = u + 0x7fffu + ((u >> 16) & 1u);
    return (u16)(r >> 16);
}
__device__ __forceinline__ float bfhi2f(unsigned v){ return __uint_as_float(v & 0xFFFF0000u); }
__device__ __forceinline__ float bflo2f(unsigned v){ return __uint_as_float(v << 16); }

// async global->LDS, 16B per lane; LDS dest is wave-uniform base + lane*16 (HW), src is per-lane
#define GLOAD_LDS16(g, l) __builtin_amdgcn_global_load_lds( \
        (const __attribute__((address_space(1))) void*)(g), \
        (__attribute__((address_space(3))) void*)(l), 16, 0, 0)

// ================= fused front-end: roi | prep(w1) | prep(w2) | rowidx ====================

__device__ __forceinline__ void prep_body(char* smem, const float* __restrict__ in,
                                          u16* __restrict__ out, int pb,
                                          int cbShift, int CShift){
    u16* lds = (u16*)smem;                             // [Cb][27] u16, linear
    const int Cb = 1 << cbShift;
    const int C  = 1 << CShift;
    const int splitShift = CShift - cbShift;           // = 1
    const int oc  = pb >> splitShift;
    const int ic0 = (pb & ((1 << splitShift) - 1)) << cbShift;
    const int n4 = (27 << cbShift) >> 2;               // float4 count
    const int tid = threadIdx.x;

    const float4* src = (const float4*)(in + ((size_t)oc * C + ic0) * 27);
#pragma unroll 4
    for (int i = tid; i < n4; i += 256){
        float4 v = src[i];
        ushort4 o;
        o.x = f2bf(v.x); o.y = f2bf(v.y); o.z = f2bf(v.z); o.w = f2bf(v.w);
        *(ushort4*)&lds[i * 4] = o;
    }
    __syncthreads();
    u16* dst = out + (size_t)oc * 27 * C + ic0;
#pragma unroll 4
    for (int j = tid; j < n4; j += 256){
        const int jj  = j << 2;
        const int tap = jj >> cbShift;
        const int icl = jj & (Cb - 1);
        ushort4 o;
        o.x = lds[(icl    ) * 27 + tap];
        o.y = lds[(icl + 1) * 27 + tap];
        o.z = lds[(icl + 2) * 27 + tap];
        o.w = lds[(icl + 3) * 27 + tap];
        *(ushort4*)(dst + (size_t)tap * C + icl) = o;
    }
}

__device__ __forceinline__ void roi_body(char* smem, const float* __restrict__ fmaps,
                                         const float* __restrict__ boxes,
                                         u16* __restrict__ rbuf, int blk){
    float* planes = (float*)smem;                      // [64][196] fp32, 50,176 B
    int   (*offsL)[16] = (int(*)[16])(smem + 50176);   // 3,456 B
    float (*wtsL)[16]  = (float(*)[16])(smem + 50176 + 3456);
    const int tid = threadIdx.x;
    if (blk == 512){                                   // zero row 1728
        for (int c = tid; c < 1024; c += 256) rbuf[(size_t)1728 * 1024 + c] = 0;
        return;
    }
    const int f  = blk >> 4;
    const int c0 = (blk & 15) << 6;

    // 1) coalesced load: 3136 float4 = one contiguous span
    const float4* src = (const float4*)(fmaps + ((size_t)f * 1024 + c0) * 196);
    float4* dl = (float4*)planes;
    for (int i = tid; i < 3136; i += 256) dl[i] = src[i];

    // 2) per-ROI bilinear taps (threads 0..53), 0.25 averaging factor folded into weights
    if (tid < 54){
        const int b = tid / 9, sp = tid % 9;
        const int oh = sp / 3, ow = sp % 3;
        const float* bx = boxes + (f * 6 + b) * 4;
        float x1 = bx[0], y1 = bx[1], x2 = bx[2], y2 = bx[3];
        float bw = fmaxf(x2 - x1, 1.0f) * (1.0f / 3.0f);
        float bh = fmaxf(y2 - y1, 1.0f) * (1.0f / 3.0f);
        int iy0[2], iy1[2], ix0[2], ix1[2];
        float ly[2], lx[2];
#pragma unroll
        for (int s = 0; s < 2; ++s){
            float gy = (float)oh + (s + 0.5f) * 0.5f;
            float ys = y1 + bh * gy;
            float y0f = floorf(ys); y0f = fminf(fmaxf(y0f, 0.f), 13.f);
            ly[s] = fminf(fmaxf(ys - y0f, 0.f), 1.f);
            iy0[s] = (int)y0f; iy1[s] = min(iy0[s] + 1, 13);
            float gx = (float)ow + (s + 0.5f) * 0.5f;
            float xs = x1 + bw * gx;
            float x0f = floorf(xs); x0f = fminf(fmaxf(x0f, 0.f), 13.f);
            lx[s] = fminf(fmaxf(xs - x0f, 0.f), 1.f);
            ix0[s] = (int)x0f; ix1[s] = min(ix0[s] + 1, 13);
        }
        int idx = 0;
#pragma unroll
        for (int sy = 0; sy < 2; ++sy)
#pragma unroll
            for (int sx = 0; sx < 2; ++sx){
                float wy1v = ly[sy], wy0v = 1.f - wy1v;
                float wx1v = lx[sx], wx0v = 1.f - wx1v;
                offsL[tid][idx] = iy0[sy] * 14 + ix0[sx]; wtsL[tid][idx] = wy0v * wx0v * 0.25f; idx++;
                offsL[tid][idx] = iy0[sy] * 14 + ix1[sx]; wtsL[tid][idx] = wy0v * wx1v * 0.25f; idx++;
                offsL[tid][idx] = iy1[sy] * 14 + ix0[sx]; wtsL[tid][idx] = wy1v * wx0v * 0.25f; idx++;
                offsL[tid][idx] = iy1[sy] * 14 + ix1[sx]; wtsL[tid][idx] = wy1v * wx1v * 0.25f; idx++;
            }
    }
    __syncthreads();

    // 3) sample: wave wv owns channels c0+wv*16..+16, lane l = ROI (54 active)
    const int wv = tid >> 6, l = tid & 63;
    if (l < 54){
        int offr[16]; float wtr[16];
#pragma unroll
        for (int i = 0; i < 16; ++i){ offr[i] = offsL[l][i]; wtr[i] = wtsL[l][i]; }
        unsigned pk[8];
#pragma unroll
        for (int jp = 0; jp < 8; ++jp){
            const float* p0 = planes + (wv * 16 + jp * 2) * 196;
            const float* p1 = p0 + 196;
            float a0 = 0.f, a1 = 0.f;
#pragma unroll
            for (int i = 0; i < 16; ++i){
                a0 += p0[offr[i]] * wtr[i];
                a1 += p1[offr[i]] * wtr[i];
            }
            pk[jp] = (unsigned)f2bf(a0) | ((unsigned)f2bf(a1) << 16);
        }
        u16* drow = rbuf + (size_t)(f * 54 + l) * 1024 + c0 + wv * 16;
        *(u32x4*)(drow)     = (u32x4){pk[0], pk[1], pk[2], pk[3]};
        *(u32x4*)(drow + 8) = (u32x4){pk[4], pk[5], pk[6], pk[7]};
    }
}

__device__ __forceinline__ void rowidx_body(const int* __restrict__ pid,
                                            int* __restrict__ rowidx, int blk){
    int i = blk * 256 + threadIdx.x;                   // 960 = 192*5
    if (i >= 960) return;
    int fb = i / 5, t = i % 5;
    int f = fb / 6, b = fb % 6;
    int start = max(f - 2, 0);
    int end = min(start + 4, 31);
    int span = end - start;
    int g = start + (t * span) / 4;
    int p = pid[f * 6 + b];
    int r = -1;
#pragma unroll
    for (int j = 0; j < 6; ++j)
        if (pid[g * 6 + j] == p){ r = (g * 6 + j) * 9; break; }
    rowidx[i] = r;
}

__global__ __launch_bounds__(256) void front_kernel(
        const float* __restrict__ fmaps, const float* __restrict__ boxes,
        const int* __restrict__ pid,
        const float* __restrict__ w1, const float* __restrict__ w2,
        u16* __restrict__ rbuf, u16* __restrict__ Wt1, u16* __restrict__ Wt2,
        int* __restrict__ rowidx){
    extern __shared__ __align__(16) char smem[];       // 57,088 B dynamic
    const int bid = blockIdx.x;
    if (bid < 513)       roi_body(smem, fmaps, boxes, rbuf, bid);
    else if (bid < 1537) prep_body(smem, w1, Wt1, bid - 513, 9, 10);
    else if (bid < 2049) prep_body(smem, w2, Wt2, bid - 1537, 8, 9);
    else                 rowidx_body(pid, rowidx, bid - 2049);
}

// ---------------- stage A: per-tap GEMM  P[tap][mb][r][128] = rbuf[r] . Wt1[oc][tap] ------
// m97 structure: 128x128 tile, BK=64, global_load_lds w16, linear LDS [128][64] u16 with
// XOR bank-swizzle applied as pre-swizzled GLOBAL source + swizzled ds_read (rule #21).
// P stores are REGULAR (not NT): reduce_kernel re-reads ~233 MB of P; keep it L3-resident.
__global__ __launch_bounds__(256, 4) void tapgemm_kernel(
        const u16* __restrict__ Wt1,     // [512][27][1024] bf16
        const u16* __restrict__ rb,      // [1729][1024] bf16 (row 1728 = 0)
        u16* __restrict__ P)             // [27][4][1728][128] bf16 (block-contiguous tiles)
{
    __shared__ u16 lds[16384];           // 32 KB: As [128][64] + Bs [128][64]
    u16* As = lds;
    u16* Bs = lds + 8192;
    const int tid = threadIdx.x;
    const int m0 = blockIdx.x * 128;     // oc
    const int n0 = blockIdx.y * 128;     // r
    const int tap = blockIdx.z;

    // ---- staging geometry: issue (w,j) covers rows w*32+j*8 .. +8 of the 128x64 tile ----
    const int w   = tid >> 6;            // wave
    const int l   = tid & 63;
    const int sub = l >> 3;              // row within 8-row group
    const int csw = (l & 7) ^ sub;       // logical K-chunk for this lane (pre-swizzled source)
    const int rowb = w * 32 + sub;
    const char* gA = (const char*)Wt1 + (size_t)(m0 + rowb) * 55296 + tap * 2048 + csw * 16;
    const char* gB[4];
#pragma unroll
    for (int j = 0; j < 4; ++j){
        int gr = min(n0 + rowb + j * 8, 1728);       // clamp to zero row
        gB[j] = (const char*)rb + (size_t)gr * 2048 + csw * 16;
    }

    const int lane = tid & 63, wv = tid >> 6;
    const int wm = (wv & 1) * 64, wn = (wv >> 1) * 64;
    const int lid = lane & 15, q = lane >> 4;
    const int xr = (lid & 7) << 4;       // read-side swizzle (row&7 == lid&7 for all frags)
    f32x4 acc[4][4];
#pragma unroll
    for (int i = 0; i < 4; ++i)
#pragma unroll
        for (int j = 0; j < 4; ++j) acc[i][j] = (f32x4){0.f, 0.f, 0.f, 0.f};

    for (int kt = 0; kt < 16; ++kt){
        __syncthreads();                 // prior tile fully consumed
#pragma unroll
        for (int j = 0; j < 4; ++j)
            GLOAD_LDS16(gA + (size_t)j * 442368 + kt * 128, &As[(w * 4 + j) * 512]);
#pragma unroll
        for (int j = 0; j < 4; ++j)
            GLOAD_LDS16(gB[j] + kt * 128, &Bs[(w * 4 + j) * 512]);
        __syncthreads();                 // vmcnt drain: staged data visible
#pragma unroll
        for (int ks = 0; ks < 2; ++ks){
            s16x8 af[4], bf[4];
            const int cb = ks * 64 + q * 16;
#pragma unroll
            for (int mi = 0; mi < 4; ++mi)
                af[mi] = *(const s16x8*)((const char*)As + (wm + mi * 16 + lid) * 128 + (cb ^ xr));
#pragma unroll
            for (int ni = 0; ni < 4; ++ni)
                bf[ni] = *(const s16x8*)((const char*)Bs + (wn + ni * 16 + lid) * 128 + (cb ^ xr));
#pragma unroll
            for (int mi = 0; mi < 4; ++mi)
#pragma unroll
                for (int ni = 0; ni < 4; ++ni)
                    acc[mi][ni] = __builtin_amdgcn_mfma_f32_16x16x32_bf16(af[mi], bf[ni], acc[mi][ni], 0, 0, 0);
        }
    }

    // ---- epilogue: LDS-transpose (swizzled, [128 r][256 B]) + contiguous writeout ----
    __syncthreads();
#pragma unroll
    for (int mi = 0; mi < 4; ++mi){
        const int colb = (wm + mi * 16 + q * 4) * 2;   // oc-local byte col
#pragma unroll
        for (int ni = 0; ni < 4; ++ni){
            const int row = wn + ni * 16 + lid;        // r-local
            ushort4 o;
            o.x = f2bf(acc[mi][ni][0]);
            o.y = f2bf(acc[mi][ni][1]);
            o.z = f2bf(acc[mi][ni][2]);
            o.w = f2bf(acc[mi][ni][3]);
            *(ushort4*)((char*)lds + row * 256 + (colb ^ xr)) = o;
        }
    }
    __syncthreads();
    // block tile = ONE contiguous 32 KB span of P; full-line stores, cache-resident
    u16* Pt = P + (((size_t)tap * 4 + blockIdx.x) * 1728 + n0) * 128;
    const int trow = tid >> 4;          // 0..15
    const int c    = tid & 15;          // 16 B chunk within the 256 B row
#pragma unroll
    for (int it = 0; it < 8; ++it){
        const int rl = it * 16 + trow;
        if (n0 + rl < 1728){
            const int pc = (c & 8) | ((c & 7) ^ (rl & 7));
            u32x4 v = *(const u32x4*)((const char*)lds + rl * 256 + pc * 16);
            *(u32x4*)(Pt + (size_t)rl * 128 + c * 8) = v;
        }
    }
}

// ---------------- stage B: y[n][oc] = relu(b1 + sum_tap P[tap][mb][src][128]) -------------
// Single-wave blocks, 16 B/lane loads: 4x fewer memory instructions than the 4 B version.
__global__ __launch_bounds__(64) void reduce_kernel(
        const unsigned* __restrict__ P32,   // [27][4][1728][64] (u32 = 2 bf16)
        const int* __restrict__ rowidx,     // [192][5]
        const float* __restrict__ b1,       // [512]
        unsigned* __restrict__ y32)         // [8640][256]
{
    __shared__ int rows[27];
    const int n = blockIdx.x;             // 0..8639
    const int tid = threadIdx.x;          // 0..63
    const int fb = n / 45, rr = n % 45;
    const int od = rr / 9, oh = (rr % 9) / 3, ow = rr % 3;
    if (tid < 27){
        int kd = tid / 9, kh = (tid % 9) / 3, kw = tid % 3;
        int t = od + kd - 1, h = oh + kh - 1, w = ow + kw - 1;
        int row = -1;
        if ((unsigned)t < 5u && (unsigned)h < 3u && (unsigned)w < 3u){
            int rbv = rowidx[fb * 5 + t];
            if (rbv >= 0) row = rbv + h * 3 + w;
        }
        rows[tid] = row;
    }
    __syncthreads();
    const int mb = tid >> 4;              // oc-block (128 oc = 64 u32) of this lane's 16 B
    const int q4 = (tid & 15) * 4;        // u32 offset within the 64-u32 segment
    float a0[4] = {0.f, 0.f, 0.f, 0.f};
    float a1[4] = {0.f, 0.f, 0.f, 0.f};
#pragma unroll
    for (int tap = 0; tap < 27; ++tap){
        int r = rows[tap];
        if (r >= 0){
            u32x4 v = *(const u32x4*)(P32 + ((((size_t)tap * 4 + mb) * 1728 + r) << 6) + q4);
#pragma unroll
            for (int k = 0; k < 4; ++k){
                a0[k] += bflo2f(v[k]);
                a1[k] += bfhi2f(v[k]);
            }
        }
    }
    const int j0 = mb * 64 + q4;          // u32 index within the 256-u32 y row
    u32x4 o;
#pragma unroll
    for (int k = 0; k < 4; ++k){
        float x0 = fmaxf(a0[k] + b1[(j0 + k) * 2], 0.f);
        float x1 = fmaxf(a1[k] + b1[(j0 + k) * 2 + 1], 0.f);
        o[k] = (unsigned)f2bf(x0) | ((unsigned)f2bf(x1) << 16);
    }
    *(u32x4*)(y32 + (size_t)n * 256 + j0) = o;
}

// ---------------- GEMM2: conv1b, 64x64 tile, BK=64, split-K=27 (one tap per split) --------
__global__ __launch_bounds__(256, 4) void gemm2_kernel(
        const u16* __restrict__ Wt2,   // [256][13824] bf16, k = tap*512+ic
        const u16* __restrict__ y,     // [8640][512] bf16; row n=fb*45+od*9+sp
        float* __restrict__ zpart)     // [27][4][576][64] f32
{
    __shared__ u16 lds[8192];          // 16 KB: As [64][64] + Bs [64][64] u16
    u16* As = lds;
    u16* Bs = lds + 4096;
    const int tid = threadIdx.x;
    const int m0 = blockIdx.x * 64;    // oc2
    const int n0 = blockIdx.y * 64;    // n (fb*3+od)
    const int kz = blockIdx.z;         // tap 0..26

    // staging geometry: wave w, issue j covers rows w*16+j*8..+8 of the 64x64 tile
    const int w   = tid >> 6;
    const int l   = tid & 63;
    const int sub = l >> 3;
    const int csw = (l & 7) ^ sub;     // pre-swizzled source K-chunk
    const int rowb = w * 16 + sub;
    const char* gA = (const char*)Wt2 + (size_t)(m0 + rowb) * 27648 + kz * 1024 + csw * 16;
    const char* gB[2];
#pragma unroll
    for (int j = 0; j < 2; ++j){
        const int n2 = n0 + rowb + j * 8;
        const int fb = n2 / 3, od2 = n2 - fb * 3;
        gB[j] = (const char*)y + ((size_t)(fb * 45 + od2 * 9) + kz) * 1024 + csw * 16;
    }

    const int lane = tid & 63, wv = tid >> 6;
    const int wm = (wv & 1) * 32, wn = (wv >> 1) * 32;
    const int lid = lane & 15, q = lane >> 4;
    const int xr = (lid & 7) << 4;
    f32x4 acc[2][2];
#pragma unroll
    for (int i = 0; i < 2; ++i)
#pragma unroll
        for (int j = 0; j < 2; ++j) acc[i][j] = (f32x4){0.f, 0.f, 0.f, 0.f};

    for (int kt = 0; kt < 8; ++kt){
        __syncthreads();
#pragma unroll
        for (int j = 0; j < 2; ++j)
            GLOAD_LDS16(gA + (size_t)j * 221184 + kt * 128, &As[(w * 2 + j) * 512]);
#pragma unroll
        for (int j = 0; j < 2; ++j)
            GLOAD_LDS16(gB[j] + kt * 128, &Bs[(w * 2 + j) * 512]);
        __syncthreads();
#pragma unroll
        for (int ks = 0; ks < 2; ++ks){
            s16x8 af[2], bf[2];
            const int cb = ks * 64 + q * 16;
#pragma unroll
            for (int mi = 0; mi < 2; ++mi)
                af[mi] = *(const s16x8*)((const char*)As + (wm + mi * 16 + lid) * 128 + (cb ^ xr));
#pragma unroll
            for (int ni = 0; ni < 2; ++ni)
                bf[ni] = *(const s16x8*)((const char*)Bs + (wn + ni * 16 + lid) * 128 + (cb ^ xr));
#pragma unroll
            for (int mi = 0; mi < 2; ++mi)
#pragma unroll
                for (int ni = 0; ni < 2; ++ni)
                    acc[mi][ni] = __builtin_amdgcn_mfma_f32_16x16x32_bf16(af[mi], bf[ni], acc[mi][ni], 0, 0, 0);
        }
    }

    // ---- epilogue: stage f32 tile [64 n][64 oc] in LDS (swizzled) + contiguous out ----
    __syncthreads();
#pragma unroll
    for (int mi = 0; mi < 2; ++mi){
        const int colb = (wm + mi * 16 + q * 4) * 4;   // oc-local byte col (f32)
#pragma unroll
        for (int ni = 0; ni < 2; ++ni){
            const int row = wn + ni * 16 + lid;        // n-local
            *(f32x4*)((char*)lds + row * 256 + (colb ^ xr)) = acc[mi][ni];
        }
    }
    __syncthreads();
    float* zb = zpart + (((size_t)kz * 4 + blockIdx.x) * 576 + n0) * 64;
    const int trow = tid >> 4;          // 0..15
    const int c    = tid & 15;          // 16 B chunk within the 256 B row
#pragma unroll
    for (int it = 0; it < 4; ++it){
        const int rl = it * 16 + trow;
        const int pc = (c & 8) | ((c & 7) ^ (rl & 7));
        u32x4 v = *(const u32x4*)((const char*)lds + rl * 256 + pc * 16);
        *(u32x4*)(zb + (size_t)rl * 64 + c * 4) = v;
    }
}

// ---------------- final: sum split-K + bias + relu + max over D + FC 256->27 (fp32 out) ----
__global__ __launch_bounds__(256) void final_kernel(
        const float* __restrict__ zpart,   // [27][4][576][64]
        const float* __restrict__ b2,
        const float* __restrict__ fcw, const float* __restrict__ fcb,
        float* __restrict__ out){
    __shared__ float smv[256];
    const int fb = blockIdx.x, tid = threadIdx.x;
    const int mb = tid >> 6, c = tid & 63;       // oc = mb*64 + c = tid
    const float bias = b2[tid];
    float mv = 0.f;
#pragma unroll
    for (int od = 0; od < 3; ++od){
        const int n = fb * 3 + od;
        float s = 0.f;
#pragma unroll
        for (int kz = 0; kz < 27; ++kz)
            s += zpart[(((size_t)kz * 4 + mb) * 576 + n) * 64 + c];
        s = fmaxf(s + bias, 0.f);
        mv = fmaxf(mv, s);
    }
    smv[tid] = mv;
    __syncthreads();
    const int wv = tid >> 6, lane = tid & 63;
    for (int cls = wv; cls < 27; cls += 4){
        const float* wrow = fcw + cls * 256;
        float s = 0.f;
#pragma unroll
        for (int j = 0; j < 4; ++j) s += smv[lane + j * 64] * wrow[lane + j * 64];
#pragma unroll
        for (int off = 32; off > 0; off >>= 1) s += __shfl_xor(s, off);
        if (lane == 0) out[fb * 27 + cls] = s + fcb[cls];
    }
}

extern "C" void kernel_launch(void* const* d_in, const int* in_sizes, int n_in,
                              void* d_out, int out_size, void* d_ws, size_t ws_size,
                              hipStream_t stream){
    const float* fmaps = (const float*)d_in[0];
    const float* boxes = (const float*)d_in[1];
    const int*   pid   = (const int*)d_in[2];
    const float* w1    = (const float*)d_in[3];
    const float* b1    = (const float*)d_in[4];
    const float* w2    = (const float*)d_in[5];
    const float* b2    = (const float*)d_in[6];
    const float* fcw   = (const float*)d_in[7];
    const float* fcb   = (const float*)d_in[8];
    float* out = (float*)d_out;

    // ---- workspace layout: TOTAL 86,710,528 B (86.7 MB) ----
    // [rbuf 3,541,248][rowidx 4,096][Wt1 28,311,552 | alias: y 8,847,360 + zpart 15,925,248]
    // [Wt2 7,077,888][P 47,775,744]
    char* ws = (char*)d_ws;
    u16*   rbuf  = (u16*)(ws);
    int*   rowidx= (int*)(ws + 3541248);
    u16*   Wt1   = (u16*)(ws + 3545344);
    u16*   y     = (u16*)(ws + 3545344);                    // aliases Wt1 (dead after tapgemm)
    float* zpart = (float*)(ws + 3545344 + 8847360);        // also inside Wt1 region (24.8 MB used of 28.3)
    u16*   Wt2   = (u16*)(ws + 3545344 + 28311552);
    u16*   P     = (u16*)(ws + 3545344 + 28311552 + 7077888);

    // fused front-end: roi (513) | prep w1 (1024) | prep w2 (512) | rowidx (4)
    hipLaunchKernelGGL(front_kernel, dim3(2053), dim3(256), 57088, stream,
                       fmaps, boxes, pid, w1, w2, rbuf, Wt1, Wt2, rowidx);
    hipLaunchKernelGGL(tapgemm_kernel, dim3(4, 14, 27), dim3(256), 0, stream, Wt1, rbuf, P);
    hipLaunchKernelGGL(reduce_kernel, dim3(8640), dim3(64), 0, stream,
                       (const unsigned*)P, rowidx, b1, (unsigned*)y);
    hipLaunchKernelGGL(gemm2_kernel, dim3(4, 9, 27), dim3(256), 0, stream, Wt2, y, zpart);
    hipLaunchKernelGGL(final_kernel, dim3(192), dim3(256), 0, stream, zpart, b2, fcw, fcb, out);
}

// Round 10
// 220.942 us; speedup vs baseline: 3.5750x; 1.1029x over previous
//
#include <hip/hip_runtime.h>

typedef short s16x8 __attribute__((ext_vector_type(8)));   // 8 bf16 raw bits
typedef float f32x4 __attribute__((ext_vector_type(4)));
typedef unsigned u32x4 __attribute__((ext_vector_type(4)));
typedef unsigned short u16;

__device__ __forceinline__ u16 f2bf(float x){
    unsigned u = __float_as_uint(x);
    unsigned r = u + 0x7fffu + ((u >> 16) & 1u);
    return (u16)(r >> 16);
}
__device__ __forceinline__ float bfhi2f(unsigned v){ return __uint_as_float(v & 0xFFFF0000u); }
__device__ __forceinline__ float bflo2f(unsigned v){ return __uint_as_float(v << 16); }

// async global->LDS, 16B per lane; LDS dest is wave-uniform base + lane*16 (HW), src is per-lane
#define GLOAD_LDS16(g, l) __builtin_amdgcn_global_load_lds( \
        (const __attribute__((address_space(1))) void*)(g), \
        (__attribute__((address_space(3))) void*)(l), 16, 0, 0)

// ================= fused front-end: roi | prep(w1) | prep(w2) | rowidx ====================
// Dynamic LDS is 32,000 B (roi's 32-ch chunk) so ALL front blocks fit 5/CU.
// (Round-8's 57 KB roi footprint capped prep blocks at 2/CU too — fusion tax.)

__device__ __forceinline__ void prep_body(char* smem, const float* __restrict__ in,
                                          u16* __restrict__ out, int pb,
                                          int cbShift, int CShift){
    u16* lds = (u16*)smem;                             // [Cb][27] u16, linear
    const int Cb = 1 << cbShift;
    const int C  = 1 << CShift;
    const int splitShift = CShift - cbShift;           // = 1
    const int oc  = pb >> splitShift;
    const int ic0 = (pb & ((1 << splitShift) - 1)) << cbShift;
    const int n4 = (27 << cbShift) >> 2;               // float4 count
    const int tid = threadIdx.x;

    const float4* src = (const float4*)(in + ((size_t)oc * C + ic0) * 27);
#pragma unroll 4
    for (int i = tid; i < n4; i += 256){
        float4 v = src[i];
        ushort4 o;
        o.x = f2bf(v.x); o.y = f2bf(v.y); o.z = f2bf(v.z); o.w = f2bf(v.w);
        *(ushort4*)&lds[i * 4] = o;
    }
    __syncthreads();
    u16* dst = out + (size_t)oc * 27 * C + ic0;
#pragma unroll 4
    for (int j = tid; j < n4; j += 256){
        const int jj  = j << 2;
        const int tap = jj >> cbShift;
        const int icl = jj & (Cb - 1);
        ushort4 o;
        o.x = lds[(icl    ) * 27 + tap];
        o.y = lds[(icl + 1) * 27 + tap];
        o.z = lds[(icl + 2) * 27 + tap];
        o.w = lds[(icl + 3) * 27 + tap];
        *(ushort4*)(dst + (size_t)tap * C + icl) = o;
    }
}

// block = (frame, 32-ch chunk): planes 25,088 B + taps 6,912 B = 32,000 B LDS
__device__ __forceinline__ void roi_body(char* smem, const float* __restrict__ fmaps,
                                         const float* __restrict__ boxes,
                                         u16* __restrict__ rbuf, int blk){
    float* planes = (float*)smem;                      // [32][196] fp32
    int   (*offsL)[16] = (int(*)[16])(smem + 25088);
    float (*wtsL)[16]  = (float(*)[16])(smem + 25088 + 3456);
    const int tid = threadIdx.x;
    if (blk == 1024){                                  // zero row 1728
        for (int c = tid; c < 1024; c += 256) rbuf[(size_t)1728 * 1024 + c] = 0;
        return;
    }
    const int f  = blk >> 5;
    const int c0 = (blk & 31) << 5;

    // 1) coalesced load: 1568 float4 = one contiguous 25 KB span
    const float4* src = (const float4*)(fmaps + ((size_t)f * 1024 + c0) * 196);
    float4* dl = (float4*)planes;
    for (int i = tid; i < 1568; i += 256) dl[i] = src[i];

    // 2) per-ROI bilinear taps (threads 0..53), 0.25 averaging factor folded into weights
    if (tid < 54){
        const int b = tid / 9, sp = tid % 9;
        const int oh = sp / 3, ow = sp % 3;
        const float* bx = boxes + (f * 6 + b) * 4;
        float x1 = bx[0], y1 = bx[1], x2 = bx[2], y2 = bx[3];
        float bw = fmaxf(x2 - x1, 1.0f) * (1.0f / 3.0f);
        float bh = fmaxf(y2 - y1, 1.0f) * (1.0f / 3.0f);
        int iy0[2], iy1[2], ix0[2], ix1[2];
        float ly[2], lx[2];
#pragma unroll
        for (int s = 0; s < 2; ++s){
            float gy = (float)oh + (s + 0.5f) * 0.5f;
            float ys = y1 + bh * gy;
            float y0f = floorf(ys); y0f = fminf(fmaxf(y0f, 0.f), 13.f);
            ly[s] = fminf(fmaxf(ys - y0f, 0.f), 1.f);
            iy0[s] = (int)y0f; iy1[s] = min(iy0[s] + 1, 13);
            float gx = (float)ow + (s + 0.5f) * 0.5f;
            float xs = x1 + bw * gx;
            float x0f = floorf(xs); x0f = fminf(fmaxf(x0f, 0.f), 13.f);
            lx[s] = fminf(fmaxf(xs - x0f, 0.f), 1.f);
            ix0[s] = (int)x0f; ix1[s] = min(ix0[s] + 1, 13);
        }
        int idx = 0;
#pragma unroll
        for (int sy = 0; sy < 2; ++sy)
#pragma unroll
            for (int sx = 0; sx < 2; ++sx){
                float wy1v = ly[sy], wy0v = 1.f - wy1v;
                float wx1v = lx[sx], wx0v = 1.f - wx1v;
                offsL[tid][idx] = iy0[sy] * 14 + ix0[sx]; wtsL[tid][idx] = wy0v * wx0v * 0.25f; idx++;
                offsL[tid][idx] = iy0[sy] * 14 + ix1[sx]; wtsL[tid][idx] = wy0v * wx1v * 0.25f; idx++;
                offsL[tid][idx] = iy1[sy] * 14 + ix0[sx]; wtsL[tid][idx] = wy1v * wx0v * 0.25f; idx++;
                offsL[tid][idx] = iy1[sy] * 14 + ix1[sx]; wtsL[tid][idx] = wy1v * wx1v * 0.25f; idx++;
            }
    }
    __syncthreads();

    // 3) sample: wave wv owns channels c0+wv*8..+8, lane l = ROI (54 active)
    const int wv = tid >> 6, l = tid & 63;
    if (l < 54){
        int offr[16]; float wtr[16];
#pragma unroll
        for (int i = 0; i < 16; ++i){ offr[i] = offsL[l][i]; wtr[i] = wtsL[l][i]; }
        unsigned pk[4];
#pragma unroll
        for (int jp = 0; jp < 4; ++jp){
            const float* p0 = planes + (wv * 8 + jp * 2) * 196;
            const float* p1 = p0 + 196;
            float a0 = 0.f, a1 = 0.f;
#pragma unroll
            for (int i = 0; i < 16; ++i){
                a0 += p0[offr[i]] * wtr[i];
                a1 += p1[offr[i]] * wtr[i];
            }
            pk[jp] = (unsigned)f2bf(a0) | ((unsigned)f2bf(a1) << 16);
        }
        u16* drow = rbuf + (size_t)(f * 54 + l) * 1024 + c0 + wv * 8;
        *(u32x4*)(drow) = (u32x4){pk[0], pk[1], pk[2], pk[3]};
    }
}

__device__ __forceinline__ void rowidx_body(const int* __restrict__ pid,
                                            int* __restrict__ rowidx, int blk){
    int i = blk * 256 + threadIdx.x;                   // 960 = 192*5
    if (i >= 960) return;
    int fb = i / 5, t = i % 5;
    int f = fb / 6, b = fb % 6;
    int start = max(f - 2, 0);
    int end = min(start + 4, 31);
    int span = end - start;
    int g = start + (t * span) / 4;
    int p = pid[f * 6 + b];
    int r = -1;
#pragma unroll
    for (int j = 0; j < 6; ++j)
        if (pid[g * 6 + j] == p){ r = (g * 6 + j) * 9; break; }
    rowidx[i] = r;
}

__global__ __launch_bounds__(256) void front_kernel(
        const float* __restrict__ fmaps, const float* __restrict__ boxes,
        const int* __restrict__ pid,
        const float* __restrict__ w1, const float* __restrict__ w2,
        u16* __restrict__ rbuf, u16* __restrict__ Wt1, u16* __restrict__ Wt2,
        int* __restrict__ rowidx){
    extern __shared__ __align__(16) char smem[];       // 32,000 B dynamic
    const int bid = blockIdx.x;
    if (bid < 1025)      roi_body(smem, fmaps, boxes, rbuf, bid);
    else if (bid < 2049) prep_body(smem, w1, Wt1, bid - 1025, 9, 10);
    else if (bid < 2561) prep_body(smem, w2, Wt2, bid - 2049, 8, 9);
    else                 rowidx_body(pid, rowidx, bid - 2561);
}

// ---------------- stage A: per-tap GEMM  P[tap][mb][r][128] = rbuf[r] . Wt1[oc][tap] ------
// m97 structure: 128x128 tile, BK=64, global_load_lds w16, linear LDS [128][64] u16 with
// XOR bank-swizzle applied as pre-swizzled GLOBAL source + swizzled ds_read (rule #21).
// P stores are REGULAR (not NT): reduce_kernel re-reads ~239 MB of P; keep it L3-resident.
__global__ __launch_bounds__(256, 4) void tapgemm_kernel(
        const u16* __restrict__ Wt1,     // [512][27][1024] bf16
        const u16* __restrict__ rb,      // [1729][1024] bf16 (row 1728 = 0)
        u16* __restrict__ P)             // [27][4][1728][128] bf16 (block-contiguous tiles)
{
    __shared__ u16 lds[16384];           // 32 KB: As [128][64] + Bs [128][64]
    u16* As = lds;
    u16* Bs = lds + 8192;
    const int tid = threadIdx.x;
    const int m0 = blockIdx.x * 128;     // oc
    const int n0 = blockIdx.y * 128;     // r
    const int tap = blockIdx.z;

    // ---- staging geometry: issue (w,j) covers rows w*32+j*8 .. +8 of the 128x64 tile ----
    const int w   = tid >> 6;            // wave
    const int l   = tid & 63;
    const int sub = l >> 3;              // row within 8-row group
    const int csw = (l & 7) ^ sub;       // logical K-chunk for this lane (pre-swizzled source)
    const int rowb = w * 32 + sub;
    const char* gA = (const char*)Wt1 + (size_t)(m0 + rowb) * 55296 + tap * 2048 + csw * 16;
    const char* gB[4];
#pragma unroll
    for (int j = 0; j < 4; ++j){
        int gr = min(n0 + rowb + j * 8, 1728);       // clamp to zero row
        gB[j] = (const char*)rb + (size_t)gr * 2048 + csw * 16;
    }

    const int lane = tid & 63, wv = tid >> 6;
    const int wm = (wv & 1) * 64, wn = (wv >> 1) * 64;
    const int lid = lane & 15, q = lane >> 4;
    const int xr = (lid & 7) << 4;       // read-side swizzle (row&7 == lid&7 for all frags)
    f32x4 acc[4][4];
#pragma unroll
    for (int i = 0; i < 4; ++i)
#pragma unroll
        for (int j = 0; j < 4; ++j) acc[i][j] = (f32x4){0.f, 0.f, 0.f, 0.f};

    for (int kt = 0; kt < 16; ++kt){
        __syncthreads();                 // prior tile fully consumed
#pragma unroll
        for (int j = 0; j < 4; ++j)
            GLOAD_LDS16(gA + (size_t)j * 442368 + kt * 128, &As[(w * 4 + j) * 512]);
#pragma unroll
        for (int j = 0; j < 4; ++j)
            GLOAD_LDS16(gB[j] + kt * 128, &Bs[(w * 4 + j) * 512]);
        __syncthreads();                 // vmcnt drain: staged data visible
#pragma unroll
        for (int ks = 0; ks < 2; ++ks){
            s16x8 af[4], bf[4];
            const int cb = ks * 64 + q * 16;
#pragma unroll
            for (int mi = 0; mi < 4; ++mi)
                af[mi] = *(const s16x8*)((const char*)As + (wm + mi * 16 + lid) * 128 + (cb ^ xr));
#pragma unroll
            for (int ni = 0; ni < 4; ++ni)
                bf[ni] = *(const s16x8*)((const char*)Bs + (wn + ni * 16 + lid) * 128 + (cb ^ xr));
#pragma unroll
            for (int mi = 0; mi < 4; ++mi)
#pragma unroll
                for (int ni = 0; ni < 4; ++ni)
                    acc[mi][ni] = __builtin_amdgcn_mfma_f32_16x16x32_bf16(af[mi], bf[ni], acc[mi][ni], 0, 0, 0);
        }
    }

    // ---- epilogue: LDS-transpose (swizzled, [128 r][256 B]) + contiguous writeout ----
    __syncthreads();
#pragma unroll
    for (int mi = 0; mi < 4; ++mi){
        const int colb = (wm + mi * 16 + q * 4) * 2;   // oc-local byte col
#pragma unroll
        for (int ni = 0; ni < 4; ++ni){
            const int row = wn + ni * 16 + lid;        // r-local
            ushort4 o;
            o.x = f2bf(acc[mi][ni][0]);
            o.y = f2bf(acc[mi][ni][1]);
            o.z = f2bf(acc[mi][ni][2]);
            o.w = f2bf(acc[mi][ni][3]);
            *(ushort4*)((char*)lds + row * 256 + (colb ^ xr)) = o;
        }
    }
    __syncthreads();
    // block tile = ONE contiguous 32 KB span of P; full-line stores, cache-resident
    u16* Pt = P + (((size_t)tap * 4 + blockIdx.x) * 1728 + n0) * 128;
    const int trow = tid >> 4;          // 0..15
    const int c    = tid & 15;          // 16 B chunk within the 256 B row
#pragma unroll
    for (int it = 0; it < 8; ++it){
        const int rl = it * 16 + trow;
        if (n0 + rl < 1728){
            const int pc = (c & 8) | ((c & 7) ^ (rl & 7));
            u32x4 v = *(const u32x4*)((const char*)lds + rl * 256 + pc * 16);
            *(u32x4*)(Pt + (size_t)rl * 128 + c * 8) = v;
        }
    }
}

// ---------------- stage B: y[n][oc] = relu(b1 + sum_tap P[tap][mb][src][128]) -------------
// Single-wave blocks, 16 B/lane loads.
__global__ __launch_bounds__(64) void reduce_kernel(
        const unsigned* __restrict__ P32,   // [27][4][1728][64] (u32 = 2 bf16)
        const int* __restrict__ rowidx,     // [192][5]
        const float* __restrict__ b1,       // [512]
        unsigned* __restrict__ y32)         // [8640][256]
{
    __shared__ int rows[27];
    const int n = blockIdx.x;             // 0..8639
    const int tid = threadIdx.x;          // 0..63
    const int fb = n / 45, rr = n % 45;
    const int od = rr / 9, oh = (rr % 9) / 3, ow = rr % 3;
    if (tid < 27){
        int kd = tid / 9, kh = (tid % 9) / 3, kw = tid % 3;
        int t = od + kd - 1, h = oh + kh - 1, w = ow + kw - 1;
        int row = -1;
        if ((unsigned)t < 5u && (unsigned)h < 3u && (unsigned)w < 3u){
            int rbv = rowidx[fb * 5 + t];
            if (rbv >= 0) row = rbv + h * 3 + w;
        }
        rows[tid] = row;
    }
    __syncthreads();
    const int mb = tid >> 4;              // oc-block (128 oc = 64 u32) of this lane's 16 B
    const int q4 = (tid & 15) * 4;        // u32 offset within the 64-u32 segment
    float a0[4] = {0.f, 0.f, 0.f, 0.f};
    float a1[4] = {0.f, 0.f, 0.f, 0.f};
#pragma unroll
    for (int tap = 0; tap < 27; ++tap){
        int r = rows[tap];
        if (r >= 0){
            u32x4 v = *(const u32x4*)(P32 + ((((size_t)tap * 4 + mb) * 1728 + r) << 6) + q4);
#pragma unroll
            for (int k = 0; k < 4; ++k){
                a0[k] += bflo2f(v[k]);
                a1[k] += bfhi2f(v[k]);
            }
        }
    }
    const int j0 = mb * 64 + q4;          // u32 index within the 256-u32 y row
    u32x4 o;
#pragma unroll
    for (int k = 0; k < 4; ++k){
        float x0 = fmaxf(a0[k] + b1[(j0 + k) * 2], 0.f);
        float x1 = fmaxf(a1[k] + b1[(j0 + k) * 2 + 1], 0.f);
        o[k] = (unsigned)f2bf(x0) | ((unsigned)f2bf(x1) << 16);
    }
    *(u32x4*)(y32 + (size_t)n * 256 + j0) = o;
}

// ---------------- GEMM2: conv1b, 64x64 tile, BK=64, split-K=27 (one tap per split) --------
__global__ __launch_bounds__(256, 4) void gemm2_kernel(
        const u16* __restrict__ Wt2,   // [256][13824] bf16, k = tap*512+ic
        const u16* __restrict__ y,     // [8640][512] bf16; row n=fb*45+od*9+sp
        float* __restrict__ zpart)     // [27][4][576][64] f32
{
    __shared__ u16 lds[8192];          // 16 KB: As [64][64] + Bs [64][64] u16
    u16* As = lds;
    u16* Bs = lds + 4096;
    const int tid = threadIdx.x;
    const int m0 = blockIdx.x * 64;    // oc2
    const int n0 = blockIdx.y * 64;    // n (fb*3+od)
    const int kz = blockIdx.z;         // tap 0..26

    // staging geometry: wave w, issue j covers rows w*16+j*8..+8 of the 64x64 tile
    const int w   = tid >> 6;
    const int l   = tid & 63;
    const int sub = l >> 3;
    const int csw = (l & 7) ^ sub;     // pre-swizzled source K-chunk
    const int rowb = w * 16 + sub;
    const char* gA = (const char*)Wt2 + (size_t)(m0 + rowb) * 27648 + kz * 1024 + csw * 16;
    const char* gB[2];
#pragma unroll
    for (int j = 0; j < 2; ++j){
        const int n2 = n0 + rowb + j * 8;
        const int fb = n2 / 3, od2 = n2 - fb * 3;
        gB[j] = (const char*)y + ((size_t)(fb * 45 + od2 * 9) + kz) * 1024 + csw * 16;
    }

    const int lane = tid & 63, wv = tid >> 6;
    const int wm = (wv & 1) * 32, wn = (wv >> 1) * 32;
    const int lid = lane & 15, q = lane >> 4;
    const int xr = (lid & 7) << 4;
    f32x4 acc[2][2];
#pragma unroll
    for (int i = 0; i < 2; ++i)
#pragma unroll
        for (int j = 0; j < 2; ++j) acc[i][j] = (f32x4){0.f, 0.f, 0.f, 0.f};

    for (int kt = 0; kt < 8; ++kt){
        __syncthreads();
#pragma unroll
        for (int j = 0; j < 2; ++j)
            GLOAD_LDS16(gA + (size_t)j * 221184 + kt * 128, &As[(w * 2 + j) * 512]);
#pragma unroll
        for (int j = 0; j < 2; ++j)
            GLOAD_LDS16(gB[j] + kt * 128, &Bs[(w * 2 + j) * 512]);
        __syncthreads();
#pragma unroll
        for (int ks = 0; ks < 2; ++ks){
            s16x8 af[2], bf[2];
            const int cb = ks * 64 + q * 16;
#pragma unroll
            for (int mi = 0; mi < 2; ++mi)
                af[mi] = *(const s16x8*)((const char*)As + (wm + mi * 16 + lid) * 128 + (cb ^ xr));
#pragma unroll
            for (int ni = 0; ni < 2; ++ni)
                bf[ni] = *(const s16x8*)((const char*)Bs + (wn + ni * 16 + lid) * 128 + (cb ^ xr));
#pragma unroll
            for (int mi = 0; mi < 2; ++mi)
#pragma unroll
                for (int ni = 0; ni < 2; ++ni)
                    acc[mi][ni] = __builtin_amdgcn_mfma_f32_16x16x32_bf16(af[mi], bf[ni], acc[mi][ni], 0, 0, 0);
        }
    }

    // ---- epilogue: stage f32 tile [64 n][64 oc] in LDS (swizzled) + contiguous out ----
    __syncthreads();
#pragma unroll
    for (int mi = 0; mi < 2; ++mi){
        const int colb = (wm + mi * 16 + q * 4) * 4;   // oc-local byte col (f32)
#pragma unroll
        for (int ni = 0; ni < 2; ++ni){
            const int row = wn + ni * 16 + lid;        // n-local
            *(f32x4*)((char*)lds + row * 256 + (colb ^ xr)) = acc[mi][ni];
        }
    }
    __syncthreads();
    float* zb = zpart + (((size_t)kz * 4 + blockIdx.x) * 576 + n0) * 64;
    const int trow = tid >> 4;          // 0..15
    const int c    = tid & 15;          // 16 B chunk within the 256 B row
#pragma unroll
    for (int it = 0; it < 4; ++it){
        const int rl = it * 16 + trow;
        const int pc = (c & 8) | ((c & 7) ^ (rl & 7));
        u32x4 v = *(const u32x4*)((const char*)lds + rl * 256 + pc * 16);
        *(u32x4*)(zb + (size_t)rl * 64 + c * 4) = v;
    }
}

// ---------------- final: sum split-K + bias + relu + max over D + FC 256->27 (fp32 out) ----
// 1024 threads: 4 groups split the 27-way kz sum (16 waves/block for latency hiding).
__global__ __launch_bounds__(1024) void final_kernel(
        const float* __restrict__ zpart,   // [27][4][576][64]
        const float* __restrict__ b2,
        const float* __restrict__ fcw, const float* __restrict__ fcb,
        float* __restrict__ out){
    __shared__ float part[4][3][256];
    __shared__ float smv[256];
    const int fb = blockIdx.x, tid = threadIdx.x;
    const int g = tid >> 8, oc = tid & 255;
    const int mb = oc >> 6, c = oc & 63;
    const int kz0 = g * 7, kz1 = min(kz0 + 7, 27);
    float s[3] = {0.f, 0.f, 0.f};
    for (int kz = kz0; kz < kz1; ++kz){
#pragma unroll
        for (int od = 0; od < 3; ++od){
            const int n = fb * 3 + od;
            s[od] += zpart[(((size_t)kz * 4 + mb) * 576 + n) * 64 + c];
        }
    }
#pragma unroll
    for (int od = 0; od < 3; ++od) part[g][od][oc] = s[od];
    __syncthreads();
    if (g == 0){
        const float bias = b2[oc];
        float mv = 0.f;
#pragma unroll
        for (int od = 0; od < 3; ++od){
            float t = part[0][od][oc] + part[1][od][oc] + part[2][od][oc] + part[3][od][oc];
            t = fmaxf(t + bias, 0.f);
            mv = fmaxf(mv, t);
        }
        smv[oc] = mv;
    }
    __syncthreads();
    if (g == 0){
        const int wv = oc >> 6, lane = oc & 63;
        for (int cls = wv; cls < 27; cls += 4){
            const float* wrow = fcw + cls * 256;
            float s2 = 0.f;
#pragma unroll
            for (int j = 0; j < 4; ++j) s2 += smv[lane + j * 64] * wrow[lane + j * 64];
#pragma unroll
            for (int off = 32; off > 0; off >>= 1) s2 += __shfl_xor(s2, off);
            if (lane == 0) out[fb * 27 + cls] = s2 + fcb[cls];
        }
    }
}

extern "C" void kernel_launch(void* const* d_in, const int* in_sizes, int n_in,
                              void* d_out, int out_size, void* d_ws, size_t ws_size,
                              hipStream_t stream){
    const float* fmaps = (const float*)d_in[0];
    const float* boxes = (const float*)d_in[1];
    const int*   pid   = (const int*)d_in[2];
    const float* w1    = (const float*)d_in[3];
    const float* b1    = (const float*)d_in[4];
    const float* w2    = (const float*)d_in[5];
    const float* b2    = (const float*)d_in[6];
    const float* fcw   = (const float*)d_in[7];
    const float* fcb   = (const float*)d_in[8];
    float* out = (float*)d_out;

    // ---- workspace layout: TOTAL 86,710,528 B (86.7 MB) ----
    // [rbuf 3,541,248][rowidx 4,096][Wt1 28,311,552 | alias: y 8,847,360 + zpart 15,925,248]
    // [Wt2 7,077,888][P 47,775,744]
    char* ws = (char*)d_ws;
    u16*   rbuf  = (u16*)(ws);
    int*   rowidx= (int*)(ws + 3541248);
    u16*   Wt1   = (u16*)(ws + 3545344);
    u16*   y     = (u16*)(ws + 3545344);                    // aliases Wt1 (dead after tapgemm)
    float* zpart = (float*)(ws + 3545344 + 8847360);        // also inside Wt1 region (24.8 MB used of 28.3)
    u16*   Wt2   = (u16*)(ws + 3545344 + 28311552);
    u16*   P     = (u16*)(ws + 3545344 + 28311552 + 7077888);

    // fused front-end: roi (1025) | prep w1 (1024) | prep w2 (512) | rowidx (4)
    hipLaunchKernelGGL(front_kernel, dim3(2565), dim3(256), 32000, stream,
                       fmaps, boxes, pid, w1, w2, rbuf, Wt1, Wt2, rowidx);
    hipLaunchKernelGGL(tapgemm_kernel, dim3(4, 14, 27), dim3(256), 0, stream, Wt1, rbuf, P);
    hipLaunchKernelGGL(reduce_kernel, dim3(8640), dim3(64), 0, stream,
                       (const unsigned*)P, rowidx, b1, (unsigned*)y);
    hipLaunchKernelGGL(gemm2_kernel, dim3(4, 9, 27), dim3(256), 0, stream, Wt2, y, zpart);
    hipLaunchKernelGGL(final_kernel, dim3(192), dim3(1024), 0, stream, zpart, b2, fcw, fcb, out);
}